// Round 2
// baseline (25806.137 us; speedup 1.0000x reference)
//
#include <hip/hip_runtime.h>
#include <stdint.h>

#define NB 256
#define NBATCH 128
#define HID 64
#define MAXEV 5
#define MAXSTEPS 256
#define NT 43          /* 43*6 = 258 >= 256 */
#define NTILES 946     /* 43*44/2 */
#define W2S 65         /* padded LDS stride for W2 rows */
#define CAND_MAX 6144

struct EvRec { int code; int i; int jw; float dte; };      // 1 ball_a, 2 ball_b, 3 wall_a, 4 wall_b
struct StepLog { int n_ev; float final_dte; EvRec ev[MAXEV]; };

__device__ __forceinline__ float bf2f(unsigned short u) {
    return __uint_as_float(((unsigned)u) << 16);
}
__device__ __forceinline__ unsigned short f2bf(float f) {
    unsigned u = __float_as_uint(f);
    u += 0x7FFFu + ((u >> 16) & 1u);
    return (unsigned short)(u >> 16);
}
__device__ __forceinline__ float rdin(const void* p, int idx, int bf) {
    return bf ? bf2f(((const unsigned short*)p)[idx]) : ((const float*)p)[idx];
}
__device__ __forceinline__ float silu_f(float x) {
    float s = __fdiv_rn(1.0f, __fadd_rn(1.0f, expf(-x)));
    return __fmul_rn(x, s);
}
__device__ __forceinline__ unsigned long long shfl_down_u64(unsigned long long v, int off) {
    unsigned lo = (unsigned)v, hi = (unsigned)(v >> 32);
    lo = __shfl_down(lo, off);
    hi = __shfl_down(hi, off);
    return (((unsigned long long)hi) << 32) | lo;
}

__device__ void load_weights(float* w1, float* b1s, float* w2, float* b2s, float* w3, float* b3s,
                             const void* W1, const void* B1, const void* W2, const void* B2,
                             const void* W3, const void* B3, int bf, int tid, int nthr) {
    for (int k = tid; k < HID * 2; k += nthr) w1[k] = rdin(W1, k, bf);
    for (int k = tid; k < HID; k += nthr) {
        b1s[k] = rdin(B1, k, bf);
        b2s[k] = rdin(B2, k, bf);
        w3[k]  = rdin(W3, k, bf);
    }
    for (int k = tid; k < HID * HID; k += nthr) {
        int m = k >> 6, c = k & 63;
        w2[m * W2S + c] = rdin(W2, k, bf);
    }
    if (tid == 0) b3s[0] = rdin(B3, 0, bf);
}

// exact-reference pair evaluation; updates min-key kP
__device__ __forceinline__ void pair_min(const float4* ps, int i, int j, unsigned long long& kP) {
    float4 A = ps[i], B = ps[j];
    float dx = __fsub_rn(B.x, A.x), dy = __fsub_rn(B.y, A.y);
    float d2 = __fadd_rn(__fmul_rn(dx, dx), __fmul_rn(dy, dy));
    float p1 = __fmul_rn(__fsub_rn(B.z, A.z), dx);
    float p2 = __fmul_rn(__fsub_rn(B.w, A.w), dy);
    float dot = __fadd_rn(p1, p2);
    float mag = __fadd_rn(fabsf(p1), fabsf(p2));
    bool appr;
    if (fabsf(dot) < __fmul_rn(1e-5f, mag)) {
        float dist = __fsqrt_rn(d2);
        float den = __fadd_rn(dist, 1e-8f);
        float ab = __fadd_rn(__fmul_rn(__fsub_rn(B.z, A.z), __fdiv_rn(dx, den)),
                             __fmul_rn(__fsub_rn(B.w, A.w), __fdiv_rn(dy, den)));
        appr = ab < 0.0f;
    } else {
        appr = dot < 0.0f;
    }
    if (appr) {
        unsigned long long key = (((unsigned long long)__float_as_uint(d2)) << 16) |
                                 (unsigned)((i << 8) | j);
        kP = key < kP ? key : kP;
    }
}

// wave-synchronous detect (64 lanes). Result min-keys valid on lane 0.
__device__ __forceinline__ void wave_detect(const float4* ps, const float* rad,
        const unsigned* cand, int nc, bool fullscan, int lane,
        unsigned long long& mP, unsigned long long& mW) {
    unsigned long long kP = ~0ull, kW = ~0ull;
    if (fullscan) {
        for (int t = lane; t < NTILES; t += 64) {
            int rem = t, r = 0;
            while (rem >= NT - r) { rem -= NT - r; r++; }
            int i0 = r * 6, j0 = (r + rem) * 6;
            for (int a = 0; a < 6; a++) {
                int i = i0 + a; if (i >= NB) break;
                for (int b = 0; b < 6; b++) {
                    int j = j0 + b;
                    if (j >= NB || j <= i) continue;
                    pair_min(ps, i, j, kP);
                }
            }
        }
    } else {
        for (int c = lane; c < nc; c += 64) {
            unsigned id = cand[c];
            pair_min(ps, (int)(id >> 8), (int)(id & 255u), kP);
        }
    }
    for (int q = lane; q < NB * 4; q += 64) {
        int ball = q >> 2, w = q & 3;
        float4 P = ps[ball]; float r = rad[ball];
        float g; bool valid;
        if (w == 0)      { g = __fsub_rn(P.x, r); valid = P.z < 0.0f; }
        else if (w == 1) { g = __fsub_rn(__fsub_rn(10.0f, P.x), r); valid = P.z > 0.0f; }
        else if (w == 2) { g = __fsub_rn(P.y, r); valid = P.w < 0.0f; }
        else             { g = __fsub_rn(__fsub_rn(10.0f, P.y), r); valid = P.w > 0.0f; }
        if (valid) {
            unsigned gb = __float_as_uint(g);
            unsigned m = (unsigned)(((int)gb) >> 31) | 0x80000000u;
            unsigned sb = gb ^ m;
            unsigned long long key = (((unsigned long long)sb) << 16) | (unsigned)q;
            kW = key < kW ? key : kW;
        }
    }
    #pragma unroll
    for (int off = 32; off; off >>= 1) {
        unsigned long long o1 = shfl_down_u64(kP, off);
        unsigned long long o2 = shfl_down_u64(kW, off);
        kP = o1 < kP ? o1 : kP;
        kW = o2 < kW ? o2 : kW;
    }
    mP = kP; mW = kW;
}

__device__ __forceinline__ void wave_integrate(float4* ps, float dte, int lane) {
    for (int b = lane; b < NB; b += 64) {
        float4 P = ps[b];
        P.x = __fadd_rn(P.x, __fmul_rn(P.z, dte));
        P.y = __fadd_rn(P.y, __fmul_rn(P.w, dte));
        ps[b] = P;
    }
    __builtin_amdgcn_wave_barrier();
    __threadfence_block();
}

// wave-synchronous MLP impulse apply; returns (lane0) max new speed of the two balls
__device__ __forceinline__ float wave_apply_ball(float4* ps, const float* w1, const float* b1s,
        const float* w2, const float* b2s, const float* w3s, float b3v, int i, int j, int lane) {
    float4 A = ps[i], B = ps[j];                 // broadcast LDS reads, identical on all lanes
    float dx = __fsub_rn(B.x, A.x), dy = __fsub_rn(B.y, A.y);
    float nrm = __fsqrt_rn(__fadd_rn(__fmul_rn(dx, dx), __fmul_rn(dy, dy)));
    float dist = fmaxf(nrm, 1e-8f);
    float nx = __fdiv_rn(dx, dist), ny = __fdiv_rn(dy, dist);
    float dvx = __fsub_rn(B.z, A.z), dvy = __fsub_rn(B.w, A.w);
    float app = __fadd_rn(__fmul_rn(dvx, nx), __fmul_rn(dvy, ny));
    // layer 1: lane = hidden unit
    float h1 = silu_f(__fadd_rn(__fadd_rn(__fmul_rn(dist, w1[2 * lane]),
                                          __fmul_rn(app, w1[2 * lane + 1])), b1s[lane]));
    // layer 2: sequential k (reference sum order), h1 broadcast via shfl
    float acc = 0.0f;
    const float* row = &w2[lane * W2S];
    for (int k = 0; k < HID; k++)
        acc = __fadd_rn(acc, __fmul_rn(__shfl(h1, k), row[k]));
    float h2 = silu_f(__fadd_rn(acc, b2s[lane]));
    // layer 3: sequential k, identical on all lanes
    float acc3 = 0.0f;
    for (int k = 0; k < HID; k++)
        acc3 = __fadd_rn(acc3, __fmul_rn(__shfl(h2, k), w3s[k]));
    float impv = __fadd_rn(acc3, b3v);
    float ret = 0.0f;
    if (lane == 0) {
        float ix = __fmul_rn(impv, nx), iy = __fmul_rn(impv, ny);
        float4 nA = A, nB = B;
        nA.z = __fadd_rn(A.z, ix);  nA.w = __fadd_rn(A.w, iy);
        nB.z = __fadd_rn(B.z, -ix); nB.w = __fadd_rn(B.w, -iy);
        ps[i] = nA; ps[j] = nB;
        float s1 = sqrtf(nA.z * nA.z + nA.w * nA.w);
        float s2 = sqrtf(nB.z * nB.z + nB.w * nB.w);
        ret = fmaxf(s1, s2);
    }
    __builtin_amdgcn_wave_barrier();
    __threadfence_block();
    return ret;
}

// wave-synchronous wall apply; returns (lane0) the position correction magnitude
__device__ __forceinline__ float wave_apply_wall(float4* ps, const float* rad, int i, int w, int lane) {
    float ret = 0.0f;
    if (lane == 0) {
        const float wnx[4] = {1.f, -1.f, 0.f, 0.f};
        const float wny[4] = {0.f, 0.f, 1.f, -1.f};
        const float wpv[4] = {0.f, -10.f, 0.f, -10.f};
        float4 P = ps[i];
        float vn = __fadd_rn(__fmul_rn(P.z, wnx[w]), __fmul_rn(P.w, wny[w]));
        float t2 = __fmul_rn(2.0f, vn);
        float nvx = __fsub_rn(P.z, __fmul_rn(t2, wnx[w]));
        float nvy = __fsub_rn(P.w, __fmul_rn(t2, wny[w]));
        float pn = __fadd_rn(__fmul_rn(P.x, wnx[w]), __fmul_rn(P.y, wny[w]));
        float pen = fmaxf(__fsub_rn(__fadd_rn(wpv[w], rad[i]), pn), 0.0f);
        float npx = __fadd_rn(P.x, __fmul_rn(pen, wnx[w]));
        float npy = __fadd_rn(P.y, __fmul_rn(pen, wny[w]));
        float4 nP; nP.x = npx; nP.y = npy; nP.z = nvx; nP.w = nvy;
        ps[i] = nP;
        ret = pen;
    }
    __builtin_amdgcn_wave_barrier();
    __threadfence_block();
    return ret;
}

__device__ __forceinline__ void wave_store_row(void* out, int bf, int s1, int b,
                                               const float4* ps, int lane) {
    long long base = ((long long)s1 * NBATCH + b) * (NB * 4);
    for (int k = lane; k < NB; k += 64) {
        float4 P = ps[k];
        if (bf) {
            ushort4 v;
            v.x = f2bf(P.x); v.y = f2bf(P.y); v.z = f2bf(P.z); v.w = f2bf(P.w);
            ((ushort4*)((unsigned short*)out + base))[k] = v;
        } else {
            ((float4*)((float*)out + base))[k] = P;
        }
    }
}

// ---------------- dtype sniffer ----------------
__global__ void sniff_kernel(const unsigned short* st, int* ws) {
    __shared__ int ev;
    if (threadIdx.x == 0) ev = 0;
    __syncthreads();
    unsigned short u = st[threadIdx.x];
    int e = (u >> 7) & 0xFF;
    if (e >= 0x85) atomicOr(&ev, 1);
    __syncthreads();
    if (threadIdx.x == 0) ws[0] = ev ? 0 : 1;   // 1 = bf16, 0 = fp32
}

// ---------------- output row 0 = initial state (bit copy) ----------------
__global__ void row0_kernel(const void* in, void* out, const int* ws) {
    int idx = blockIdx.x * blockDim.x + threadIdx.x;
    if (ws[0]) ((unsigned short*)out)[idx] = ((const unsigned short*)in)[idx];
    else       ((float*)out)[idx] = ((const float*)in)[idx];
}

// ---------------- phase 1: batch-0 event sim (wave-sync event loop) ----------------
__global__ __launch_bounds__(1024, 1) void phase1_kernel(
    const void* in_state, const void* in_rad,
    const void* inW1, const void* inB1, const void* inW2, const void* inB2,
    const void* inW3, const void* inB3, const void* in_dt, const int* in_nsteps,
    void* out, int* ws) {
    __shared__ float4 ps[NB];
    __shared__ float rad[NB];
    __shared__ float w1[HID * 2], b1s[HID], w2[HID * W2S], b2s[HID], w3s[HID], b3s[1];
    __shared__ unsigned cand[CAND_MAX];
    __shared__ int candN;
    __shared__ int vmax2bits;
    __shared__ float dtv_s;

    int tid = threadIdx.x;
    int bf = ws[0];
    StepLog* logp = (StepLog*)(ws + 16);

    if (tid < NB) {
        float4 P;
        P.x = rdin(in_state, tid * 4 + 0, bf);
        P.y = rdin(in_state, tid * 4 + 1, bf);
        P.z = rdin(in_state, tid * 4 + 2, bf);
        P.w = rdin(in_state, tid * 4 + 3, bf);
        ps[tid] = P;
        rad[tid] = rdin(in_rad, tid, bf);
    }
    load_weights(w1, b1s, w2, b2s, w3s, b3s, inW1, inB1, inW2, inB2, inW3, inB3, bf, tid, 1024);
    if (tid == 0) {
        candN = 0;
        vmax2bits = 0;
        dtv_s = rdin(in_dt, 0, bf);
    }
    __syncthreads();
    if (tid < NB) {
        float4 P = ps[tid];
        float sp2 = P.z * P.z + P.w * P.w;
        atomicMax(&vmax2bits, __float_as_int(sp2));
    }

    float dtv = dtv_s;
    float rsum = __fadd_rn(rad[0], rad[0]);
    int NS = in_nsteps[0]; if (NS > MAXSTEPS) NS = MAXSTEPS; if (NS < 0) NS = 0;

    // tile assignment for the candidate build
    int i0 = 0, j0 = 0, hasT = 0;
    if (tid < NTILES) {
        int rem = tid, r = 0;
        while (rem >= NT - r) { rem -= NT - r; r++; }
        i0 = r * 6; j0 = (r + rem) * 6; hasT = 1;
    }

    for (int s = 0; s < NS; s++) {
        __syncthreads();   // (A) prev-step state + candN=0 + vmax2bits visible
        float vmaxv = sqrtf(fmaxf(__int_as_float(vmax2bits), 0.0f));
        float theta = rsum + 0.05f + 2.0f * dtv * vmaxv + 0.15f;
        float th2 = theta * theta;
        if (hasT) {
            float4 Pi[6], Pj[6];
            #pragma unroll
            for (int a = 0; a < 6; a++) {
                int ii = i0 + a; ii = ii < NB ? ii : NB - 1;
                int jj = j0 + a; jj = jj < NB ? jj : NB - 1;
                Pi[a] = ps[ii]; Pj[a] = ps[jj];
            }
            #pragma unroll
            for (int a = 0; a < 6; a++) {
                int i = i0 + a;
                #pragma unroll
                for (int b = 0; b < 6; b++) {
                    int j = j0 + b;
                    bool ok = (i < NB) && (j < NB) && (j > i);
                    float dx = Pj[b].x - Pi[a].x;
                    float dy = Pj[b].y - Pi[a].y;
                    float d2 = dx * dx + dy * dy;
                    if (ok && d2 < th2) {
                        int x = atomicAdd(&candN, 1);
                        if (x < CAND_MAX) cand[x] = (unsigned)((i << 8) | j);
                    }
                }
            }
        }
        __syncthreads();   // (C) candidate list complete

        if (tid < 64) {
            int lane = tid;
            float t_s = __fmul_rn((float)s, dtv);
            float t_e = __fadd_rn(t_s, dtv);
            float t_c = t_s;
            int n_ev = 0;
            float vcap = vmaxv;
            float wallacc = 0.0f;
            float margin = 2.0f * dtv * vmaxv + 0.15f;
            int candTotal = candN;
            int nc = candTotal > CAND_MAX ? CAND_MAX : candTotal;

            for (int e = 0; e < MAXEV; e++) {
                bool fullscan = (candTotal > CAND_MAX) ||
                                (2.0f * dtv * vcap + wallacc + 1e-3f > margin);
                __threadfence_block();
                unsigned long long mP, mW;
                wave_detect(ps, rad, cand, nc, fullscan, lane, mP, mW);

                int info = 0; float dteB = 0.0f, tcn = t_c;
                if (lane == 0) {
                    float gball = 1e30f; int pi = 0, pj = 1;
                    if (mP != ~0ull) {
                        unsigned id = (unsigned)(mP & 0xFFFFull);
                        pi = id >> 8; pj = id & 255u;
                        float d2 = __uint_as_float((unsigned)(mP >> 16));
                        gball = __fsub_rn(__fsqrt_rn(d2), rsum);
                    }
                    float gwall = 1e30f; int wb = 0, ww = 0;
                    if (mW != ~0ull) {
                        unsigned id = (unsigned)(mW & 0xFFFFull);
                        wb = id >> 2; ww = id & 3u;
                        unsigned sb = (unsigned)(mW >> 16);
                        unsigned gb = (sb & 0x80000000u) ? (sb ^ 0x80000000u) : ~sb;
                        gwall = __uint_as_float(gb);
                    }
                    bool is_ball = gball <= gwall;
                    float gap = is_ball ? gball : gwall;
                    int code = 0;
                    if (!(gap > 0.05f)) {
                        float app;
                        if (is_ball) {
                            float4 A = ps[pi], B = ps[pj];
                            float dx = __fsub_rn(B.x, A.x), dy = __fsub_rn(B.y, A.y);
                            float nrm = __fsqrt_rn(__fadd_rn(__fmul_rn(dx, dx), __fmul_rn(dy, dy)));
                            float dvx = __fsub_rn(B.z, A.z), dvy = __fsub_rn(B.w, A.w);
                            app = -__fadd_rn(__fdiv_rn(__fmul_rn(dvx, dx), nrm),
                                             __fdiv_rn(__fmul_rn(dvy, dy), nrm));
                        } else {
                            float4 Wb = ps[wb];
                            app = fabsf(fmaxf(Wb.z, Wb.w));
                        }
                        float t_ev = __fadd_rn(t_c, __fdiv_rn(gap, fmaxf(app, 1e-6f)));
                        if (gap <= 0.0f) {
                            code = is_ball ? 1 : 3;
                        } else if (app > 1e-6f && t_ev < t_e) {
                            code = is_ball ? 2 : 4;
                            dteB = (t_ev > __fadd_rn(t_c, 1e-10f)) ? __fsub_rn(t_ev, t_c) : 0.0f;
                            tcn = t_ev;
                        }
                    }
                    int ei = is_ball ? pi : wb;
                    int ej = is_ball ? pj : ww;
                    info = code | (ei << 3) | (ej << 11);
                    if (code != 0) {
                        EvRec er; er.code = code; er.i = ei; er.jw = ej; er.dte = dteB;
                        logp[s].ev[n_ev] = er;
                    }
                }
                info = __shfl(info, 0);
                dteB = __shfl(dteB, 0);
                tcn  = __shfl(tcn, 0);
                int code = info & 7;
                if (code == 0) break;
                int ei = (info >> 3) & 255, ejw = (info >> 11) & 255;
                if (code == 2 || code == 4) wave_integrate(ps, dteB, lane);
                if (code <= 2) {
                    float nv = wave_apply_ball(ps, w1, b1s, w2, b2s, w3s, b3s[0], ei, ejw, lane);
                    nv = __shfl(nv, 0);
                    vcap = fmaxf(vcap, nv);
                } else {
                    float pen = wave_apply_wall(ps, rad, ei, ejw, lane);
                    pen = __shfl(pen, 0);
                    wallacc += pen;
                }
                t_c = tcn;
                n_ev++;
            }

            float fd = 0.0f;
            if (lane == 0) fd = (t_e > __fadd_rn(t_c, 1e-10f)) ? __fsub_rn(t_e, t_c) : 0.0f;
            fd = __shfl(fd, 0);
            if (lane == 0) { logp[s].final_dte = fd; logp[s].n_ev = n_ev; }
            wave_integrate(ps, fd, lane);

            // vmax for next step + reset candidate counter
            float m2 = 0.0f;
            for (int b = lane; b < NB; b += 64) {
                float4 P = ps[b];
                m2 = fmaxf(m2, P.z * P.z + P.w * P.w);
            }
            #pragma unroll
            for (int off = 32; off; off >>= 1) m2 = fmaxf(m2, __shfl_down(m2, off));
            if (lane == 0) { vmax2bits = __float_as_int(m2); candN = 0; }

            wave_store_row(out, bf, s + 1, 0, ps, lane);
        }
    }
}

// ---------------- phase 2: per-batch replay (single wave per block) ----------------
__global__ __launch_bounds__(64, 1) void phase2_kernel(
    const void* in_state, const void* in_rad,
    const void* inW1, const void* inB1, const void* inW2, const void* inB2,
    const void* inW3, const void* inB3, const int* in_nsteps,
    void* out, int* ws) {
    __shared__ float4 ps[NB];
    __shared__ float rad[NB];
    __shared__ float w1[HID * 2], b1s[HID], w2[HID * W2S], b2s[HID], w3s[HID], b3s[1];

    int lane = threadIdx.x;
    int b = blockIdx.x + 1;
    int bf = ws[0];
    const StepLog* logp = (const StepLog*)(ws + 16);

    for (int k = lane; k < NB; k += 64) {
        int base = b * NB * 4 + k * 4;
        float4 P;
        P.x = rdin(in_state, base + 0, bf);
        P.y = rdin(in_state, base + 1, bf);
        P.z = rdin(in_state, base + 2, bf);
        P.w = rdin(in_state, base + 3, bf);
        ps[k] = P;
        rad[k] = rdin(in_rad, k, bf);
    }
    load_weights(w1, b1s, w2, b2s, w3s, b3s, inW1, inB1, inW2, inB2, inW3, inB3, bf, lane, 64);
    __syncthreads();

    int NS = in_nsteps[0]; if (NS > MAXSTEPS) NS = MAXSTEPS; if (NS < 0) NS = 0;

    for (int s = 0; s < NS; s++) {
        int ne = logp[s].n_ev;
        float fd = logp[s].final_dte;
        for (int e = 0; e < ne; e++) {
            EvRec er = logp[s].ev[e];
            if (er.code == 2 || er.code == 4) wave_integrate(ps, er.dte, lane);
            if (er.code <= 2) wave_apply_ball(ps, w1, b1s, w2, b2s, w3s, b3s[0], er.i, er.jw, lane);
            else              wave_apply_wall(ps, rad, er.i, er.jw, lane);
        }
        wave_integrate(ps, fd, lane);
        wave_store_row(out, bf, s + 1, b, ps, lane);
    }
}

extern "C" void kernel_launch(void* const* d_in, const int* in_sizes, int n_in,
                              void* d_out, int out_size, void* d_ws, size_t ws_size,
                              hipStream_t stream) {
    // inputs: 0 state, 1 radii, 2 W1, 3 b1, 4 W2, 5 b2, 6 W3, 7 b3, 8 dt, 9 n_steps
    int* ws = (int*)d_ws;
    sniff_kernel<<<1, 256, 0, stream>>>((const unsigned short*)d_in[0], ws);
    row0_kernel<<<(NBATCH * NB * 4) / 256, 256, 0, stream>>>(d_in[0], d_out, ws);
    phase1_kernel<<<1, 1024, 0, stream>>>(
        d_in[0], d_in[1], d_in[2], d_in[3], d_in[4], d_in[5], d_in[6], d_in[7],
        d_in[8], (const int*)d_in[9], d_out, ws);
    phase2_kernel<<<NBATCH - 1, 64, 0, stream>>>(
        d_in[0], d_in[1], d_in[2], d_in[3], d_in[4], d_in[5], d_in[6], d_in[7],
        (const int*)d_in[9], d_out, ws);
}

// Round 3
// 9762.138 us; speedup vs baseline: 2.6435x; 2.6435x over previous
//
#include <hip/hip_runtime.h>
#include <stdint.h>

#define NB 256
#define NBATCH 128
#define HID 64
#define MAXEV 5
#define MAXSTEPS 256
#define NT 43          /* 43*6 = 258 >= 256 */
#define NTILES 946     /* 43*44/2 */
#define W2S 65         /* padded LDS stride for W2 rows */
#define CAND_MAX 6144

struct EvRec { int code; int i; int jw; float dte; };      // 1 ball_a, 2 ball_b, 3 wall_a, 4 wall_b
struct StepLog { int n_ev; float final_dte; EvRec ev[MAXEV]; };

__device__ __forceinline__ float bf2f(unsigned short u) {
    return __uint_as_float(((unsigned)u) << 16);
}
__device__ __forceinline__ unsigned short f2bf(float f) {
    unsigned u = __float_as_uint(f);
    u += 0x7FFFu + ((u >> 16) & 1u);
    return (unsigned short)(u >> 16);
}
__device__ __forceinline__ float rdin(const void* p, int idx, int bf) {
    return bf ? bf2f(((const unsigned short*)p)[idx]) : ((const float*)p)[idx];
}
__device__ __forceinline__ float silu_f(float x) {
    float s = __fdiv_rn(1.0f, __fadd_rn(1.0f, expf(-x)));
    return __fmul_rn(x, s);
}
__device__ __forceinline__ unsigned long long shfl_down_u64(unsigned long long v, int off) {
    unsigned lo = (unsigned)v, hi = (unsigned)(v >> 32);
    lo = __shfl_down(lo, off);
    hi = __shfl_down(hi, off);
    return (((unsigned long long)hi) << 32) | lo;
}

__device__ void load_weights(float* w1, float* b1s, float* w2, float* b2s, float* w3, float* b3s,
                             const void* W1, const void* B1, const void* W2, const void* B2,
                             const void* W3, const void* B3, int bf, int tid, int nthr) {
    for (int k = tid; k < HID * 2; k += nthr) w1[k] = rdin(W1, k, bf);
    for (int k = tid; k < HID; k += nthr) {
        b1s[k] = rdin(B1, k, bf);
        b2s[k] = rdin(B2, k, bf);
        w3[k]  = rdin(W3, k, bf);
    }
    for (int k = tid; k < HID * HID; k += nthr) {
        int m = k >> 6, c = k & 63;
        w2[m * W2S + c] = rdin(W2, k, bf);
    }
    if (tid == 0) b3s[0] = rdin(B3, 0, bf);
}

// exact-reference pair evaluation; updates min-key kP
__device__ __forceinline__ void pair_min(const float4* ps, int i, int j, unsigned long long& kP) {
    float4 A = ps[i], B = ps[j];
    float dx = __fsub_rn(B.x, A.x), dy = __fsub_rn(B.y, A.y);
    float d2 = __fadd_rn(__fmul_rn(dx, dx), __fmul_rn(dy, dy));
    float p1 = __fmul_rn(__fsub_rn(B.z, A.z), dx);
    float p2 = __fmul_rn(__fsub_rn(B.w, A.w), dy);
    float dot = __fadd_rn(p1, p2);
    float mag = __fadd_rn(fabsf(p1), fabsf(p2));
    bool appr;
    if (fabsf(dot) < __fmul_rn(1e-5f, mag)) {
        float dist = __fsqrt_rn(d2);
        float den = __fadd_rn(dist, 1e-8f);
        float ab = __fadd_rn(__fmul_rn(__fsub_rn(B.z, A.z), __fdiv_rn(dx, den)),
                             __fmul_rn(__fsub_rn(B.w, A.w), __fdiv_rn(dy, den)));
        appr = ab < 0.0f;
    } else {
        appr = dot < 0.0f;
    }
    if (appr) {
        unsigned long long key = (((unsigned long long)__float_as_uint(d2)) << 16) |
                                 (unsigned)((i << 8) | j);
        kP = key < kP ? key : kP;
    }
}

// block-level detect (256 threads). Leaders write per-wave minima into redU[0..3]/[4..7].
__device__ void blk_detect(const float4* ps, const float* rad,
                           const unsigned* cand, int nc, bool fullscan, int tid,
                           unsigned long long* redU) {
    unsigned long long kP = ~0ull, kW = ~0ull;
    if (fullscan) {
        for (int t = tid; t < NTILES; t += 256) {
            int rem = t, r = 0;
            while (rem >= NT - r) { rem -= NT - r; r++; }
            int i0 = r * 6, j0 = (r + rem) * 6;
            for (int a = 0; a < 6; a++) {
                int i = i0 + a; if (i >= NB) break;
                for (int b = 0; b < 6; b++) {
                    int j = j0 + b;
                    if (j >= NB || j <= i) continue;
                    pair_min(ps, i, j, kP);
                }
            }
        }
    } else {
        for (int c = tid; c < nc; c += 256) {
            unsigned id = cand[c];
            pair_min(ps, (int)(id >> 8), (int)(id & 255u), kP);
        }
    }
    for (int q = tid; q < NB * 4; q += 256) {
        int ball = q >> 2, w = q & 3;
        float4 P = ps[ball]; float r = rad[ball];
        float g; bool valid;
        if (w == 0)      { g = __fsub_rn(P.x, r); valid = P.z < 0.0f; }
        else if (w == 1) { g = __fsub_rn(__fsub_rn(10.0f, P.x), r); valid = P.z > 0.0f; }
        else if (w == 2) { g = __fsub_rn(P.y, r); valid = P.w < 0.0f; }
        else             { g = __fsub_rn(__fsub_rn(10.0f, P.y), r); valid = P.w > 0.0f; }
        if (valid) {
            unsigned gb = __float_as_uint(g);
            unsigned m = (unsigned)(((int)gb) >> 31) | 0x80000000u;
            unsigned sb = gb ^ m;
            unsigned long long key = (((unsigned long long)sb) << 16) | (unsigned)q;
            kW = key < kW ? key : kW;
        }
    }
    #pragma unroll
    for (int off = 32; off; off >>= 1) {
        unsigned long long o1 = shfl_down_u64(kP, off);
        unsigned long long o2 = shfl_down_u64(kW, off);
        kP = o1 < kP ? o1 : kP;
        kW = o2 < kW ? o2 : kW;
    }
    if ((tid & 63) == 0) { redU[tid >> 6] = kP; redU[4 + (tid >> 6)] = kW; }
}

// each thread owns ball `tid` (256 threads == NB)
__device__ __forceinline__ void blk_integrate(float4* ps, float dte, int tid) {
    float4 P = ps[tid];
    P.x = __fadd_rn(P.x, __fmul_rn(P.z, dte));
    P.y = __fadd_rn(P.y, __fmul_rn(P.w, dte));
    ps[tid] = P;
    __syncthreads();
}

// round-0 proven structure; sc[140] <- max new speed of the two balls
__device__ void blk_apply_ball(float4* ps, const float* w1, const float* b1s,
                               const float* w2, const float* b2s, const float* w3s,
                               const float* b3s, float* sc, int i, int j, int tid) {
    if (tid == 0) {
        float4 A = ps[i], B = ps[j];
        float dx = __fsub_rn(B.x, A.x), dy = __fsub_rn(B.y, A.y);
        float nrm = __fsqrt_rn(__fadd_rn(__fmul_rn(dx, dx), __fmul_rn(dy, dy)));
        float dist = fmaxf(nrm, 1e-8f);
        float nx = __fdiv_rn(dx, dist), ny = __fdiv_rn(dy, dist);
        float dvx = __fsub_rn(B.z, A.z), dvy = __fsub_rn(B.w, A.w);
        float app = __fadd_rn(__fmul_rn(dvx, nx), __fmul_rn(dvy, ny));
        sc[0] = nx; sc[1] = ny; sc[2] = dist; sc[3] = app;
    }
    __syncthreads();
    if (tid < HID) {
        float a = __fadd_rn(__fadd_rn(__fmul_rn(sc[2], w1[2 * tid]),
                                      __fmul_rn(sc[3], w1[2 * tid + 1])), b1s[tid]);
        sc[4 + tid] = silu_f(a);
    }
    __syncthreads();
    if (tid < HID) {
        float acc = 0.0f;
        const float* row = &w2[tid * W2S];
        #pragma unroll 8
        for (int k = 0; k < HID; k++) acc = __fadd_rn(acc, __fmul_rn(sc[4 + k], row[k]));
        acc = __fadd_rn(acc, b2s[tid]);
        sc[68 + tid] = silu_f(acc);
    }
    __syncthreads();
    if (tid == 0) {
        float acc = 0.0f;
        for (int k = 0; k < HID; k++) acc = __fadd_rn(acc, __fmul_rn(sc[68 + k], w3s[k]));
        acc = __fadd_rn(acc, b3s[0]);
        float ix = __fmul_rn(acc, sc[0]), iy = __fmul_rn(acc, sc[1]);
        float4 A = ps[i], B = ps[j];
        A.z = __fadd_rn(A.z, ix);  A.w = __fadd_rn(A.w, iy);
        B.z = __fadd_rn(B.z, -ix); B.w = __fadd_rn(B.w, -iy);
        ps[i] = A; ps[j] = B;
        float s1 = sqrtf(A.z * A.z + A.w * A.w);
        float s2 = sqrtf(B.z * B.z + B.w * B.w);
        sc[140] = fmaxf(s1, s2);
    }
    __syncthreads();
}

// sc[141] <- wall penetration correction magnitude
__device__ void blk_apply_wall(float4* ps, const float* rad, float* sc, int i, int w, int tid) {
    if (tid == 0) {
        const float wnx[4] = {1.f, -1.f, 0.f, 0.f};
        const float wny[4] = {0.f, 0.f, 1.f, -1.f};
        const float wpv[4] = {0.f, -10.f, 0.f, -10.f};
        float4 P = ps[i];
        float vn = __fadd_rn(__fmul_rn(P.z, wnx[w]), __fmul_rn(P.w, wny[w]));
        float t2 = __fmul_rn(2.0f, vn);
        float nvx = __fsub_rn(P.z, __fmul_rn(t2, wnx[w]));
        float nvy = __fsub_rn(P.w, __fmul_rn(t2, wny[w]));
        float pn = __fadd_rn(__fmul_rn(P.x, wnx[w]), __fmul_rn(P.y, wny[w]));
        float pen = fmaxf(__fsub_rn(__fadd_rn(wpv[w], rad[i]), pn), 0.0f);
        float npx = __fadd_rn(P.x, __fmul_rn(pen, wnx[w]));
        float npy = __fadd_rn(P.y, __fmul_rn(pen, wny[w]));
        float4 nP; nP.x = npx; nP.y = npy; nP.z = nvx; nP.w = nvy;
        ps[i] = nP;
        sc[141] = pen;
    }
    __syncthreads();
}

__device__ __forceinline__ void blk_store_row(void* out, int bf, int s1, int b,
                                              const float4* ps, int tid) {
    long long base = ((long long)s1 * NBATCH + b) * (NB * 4);
    float4 P = ps[tid];
    if (bf) {
        ushort4 v;
        v.x = f2bf(P.x); v.y = f2bf(P.y); v.z = f2bf(P.z); v.w = f2bf(P.w);
        ((ushort4*)((unsigned short*)out + base))[tid] = v;
    } else {
        ((float4*)((float*)out + base))[tid] = P;
    }
}

// ---------------- dtype sniffer ----------------
__global__ void sniff_kernel(const unsigned short* st, int* ws) {
    __shared__ int ev;
    if (threadIdx.x == 0) ev = 0;
    __syncthreads();
    unsigned short u = st[threadIdx.x];
    int e = (u >> 7) & 0xFF;
    if (e >= 0x85) atomicOr(&ev, 1);
    __syncthreads();
    if (threadIdx.x == 0) ws[0] = ev ? 0 : 1;   // 1 = bf16, 0 = fp32
}

// ---------------- output row 0 = initial state (bit copy) ----------------
__global__ void row0_kernel(const void* in, void* out, const int* ws) {
    int idx = blockIdx.x * blockDim.x + threadIdx.x;
    if (ws[0]) ((unsigned short*)out)[idx] = ((const unsigned short*)in)[idx];
    else       ((float*)out)[idx] = ((const float*)in)[idx];
}

// ---------------- fused producer/consumer kernel ----------------
__global__ __launch_bounds__(256) void fused_kernel(
    const void* in_state, const void* in_rad,
    const void* inW1, const void* inB1, const void* inW2, const void* inB2,
    const void* inW3, const void* inB3, const void* in_dt, const int* in_nsteps,
    void* out, int* ws) {
    __shared__ float4 ps[NB];
    __shared__ float rad[NB];
    __shared__ float w1[HID * 2], b1s[HID], w2[HID * W2S], b2s[HID], w3s[HID], b3s[1];
    __shared__ float sc[160];
    __shared__ unsigned long long redU[8];
    __shared__ float redF[4];
    __shared__ int dI[4];
    __shared__ float dF[4];
    __shared__ unsigned cand[CAND_MAX];
    __shared__ int candN;
    __shared__ int vmax2bits;

    int tid = threadIdx.x;
    int b = blockIdx.x;
    int bf = ws[0];
    int* done = ws + 16;                               // poison 0xAAAAAAAA < 0: consumers wait
    StepLog* logp = (StepLog*)(ws + 64);

    // ---- common init: state (batch b), radii, weights ----
    {
        int base = (b * NB + tid) * 4;
        float4 P;
        P.x = rdin(in_state, base + 0, bf);
        P.y = rdin(in_state, base + 1, bf);
        P.z = rdin(in_state, base + 2, bf);
        P.w = rdin(in_state, base + 3, bf);
        ps[tid] = P;
        rad[tid] = rdin(in_rad, tid, bf);
    }
    load_weights(w1, b1s, w2, b2s, w3s, b3s, inW1, inB1, inW2, inB2, inW3, inB3, bf, tid, 256);
    __syncthreads();

    int NS = in_nsteps[0]; if (NS > MAXSTEPS) NS = MAXSTEPS; if (NS < 0) NS = 0;

    if (b == 0) {
        // ================= producer: batch-0 event simulation =================
        float dtv = rdin(in_dt, 0, bf);
        float rsum = __fadd_rn(rad[0], rad[0]);        // radii uniform

        // static tile assignment for candidate build (<=4 tiles/thread)
        int ti0[4], tj0[4], ntile = 0;
        for (int t = tid; t < NTILES; t += 256) {
            int rem = t, r = 0;
            while (rem >= NT - r) { rem -= NT - r; r++; }
            ti0[ntile] = r * 6; tj0[ntile] = (r + rem) * 6; ntile++;
        }

        // initial vmax + counter init
        {
            float4 P = ps[tid];
            float m2 = P.z * P.z + P.w * P.w;
            #pragma unroll
            for (int off = 32; off; off >>= 1) m2 = fmaxf(m2, __shfl_down(m2, off));
            if ((tid & 63) == 0) redF[tid >> 6] = m2;
            __syncthreads();
            if (tid == 0) {
                float m = fmaxf(fmaxf(redF[0], redF[1]), fmaxf(redF[2], redF[3]));
                vmax2bits = __float_as_int(m);
                candN = 0;
            }
        }

        for (int s = 0; s < NS; s++) {
            __syncthreads();   // (A) state + candN + vmax visible
            float vmaxv = sqrtf(fmaxf(__int_as_float(vmax2bits), 0.0f));
            float theta = rsum + 0.05f + 2.0f * dtv * vmaxv + 0.15f;
            float th2 = theta * theta;

            // candidate build
            for (int t = 0; t < ntile; t++) {
                int i0 = ti0[t], j0 = tj0[t];
                float4 Pi[6], Pj[6];
                #pragma unroll
                for (int a = 0; a < 6; a++) {
                    int ii = i0 + a; ii = ii < NB ? ii : NB - 1;
                    int jj = j0 + a; jj = jj < NB ? jj : NB - 1;
                    Pi[a] = ps[ii]; Pj[a] = ps[jj];
                }
                #pragma unroll
                for (int a = 0; a < 6; a++) {
                    int i = i0 + a;
                    #pragma unroll
                    for (int bb = 0; bb < 6; bb++) {
                        int j = j0 + bb;
                        bool ok = (i < NB) && (j < NB) && (j > i);
                        float dx = Pj[bb].x - Pi[a].x;
                        float dy = Pj[bb].y - Pi[a].y;
                        float d2 = dx * dx + dy * dy;
                        if (ok && d2 < th2) {
                            int x = atomicAdd(&candN, 1);
                            if (x < CAND_MAX) cand[x] = (unsigned)((i << 8) | j);
                        }
                    }
                }
            }
            __syncthreads();   // (C) candidate list complete

            float t_s = __fmul_rn((float)s, dtv);
            float t_e = __fadd_rn(t_s, dtv);
            float t_c = t_s;
            int n_ev = 0;
            float vcap = vmaxv;
            float wallacc = 0.0f;
            float margin = 2.0f * dtv * vmaxv + 0.15f;
            int candTotal = candN;
            int nc = candTotal > CAND_MAX ? CAND_MAX : candTotal;

            for (int e = 0; e < MAXEV; e++) {
                bool fullscan = (candTotal > CAND_MAX) ||
                                (2.0f * dtv * vcap + wallacc + 1e-3f > margin);
                blk_detect(ps, rad, cand, nc, fullscan, tid, redU);
                __syncthreads();
                if (tid == 0) {
                    unsigned long long mP = redU[0], mW = redU[4];
                    for (int q = 1; q < 4; q++) {
                        mP = redU[q] < mP ? redU[q] : mP;
                        mW = redU[4 + q] < mW ? redU[4 + q] : mW;
                    }
                    float gball = 1e30f; int pi = 0, pj = 1;
                    if (mP != ~0ull) {
                        unsigned id = (unsigned)(mP & 0xFFFFull);
                        pi = id >> 8; pj = id & 255u;
                        float d2 = __uint_as_float((unsigned)(mP >> 16));
                        gball = __fsub_rn(__fsqrt_rn(d2), rsum);
                    }
                    float gwall = 1e30f; int wb = 0, ww = 0;
                    if (mW != ~0ull) {
                        unsigned id = (unsigned)(mW & 0xFFFFull);
                        wb = id >> 2; ww = id & 3u;
                        unsigned sb = (unsigned)(mW >> 16);
                        unsigned gb = (sb & 0x80000000u) ? (sb ^ 0x80000000u) : ~sb;
                        gwall = __uint_as_float(gb);
                    }
                    bool is_ball = gball <= gwall;
                    float gap = is_ball ? gball : gwall;
                    int code = 0; float dteB = 0.0f, tcn = t_c;
                    if (!(gap > 0.05f)) {
                        float app;
                        if (is_ball) {
                            float4 A = ps[pi], B = ps[pj];
                            float dx = __fsub_rn(B.x, A.x), dy = __fsub_rn(B.y, A.y);
                            float nrm = __fsqrt_rn(__fadd_rn(__fmul_rn(dx, dx), __fmul_rn(dy, dy)));
                            float dvx = __fsub_rn(B.z, A.z), dvy = __fsub_rn(B.w, A.w);
                            app = -__fadd_rn(__fdiv_rn(__fmul_rn(dvx, dx), nrm),
                                             __fdiv_rn(__fmul_rn(dvy, dy), nrm));
                        } else {
                            float4 Wb = ps[wb];
                            app = fabsf(fmaxf(Wb.z, Wb.w));
                        }
                        float t_ev = __fadd_rn(t_c, __fdiv_rn(gap, fmaxf(app, 1e-6f)));
                        if (gap <= 0.0f) {
                            code = is_ball ? 1 : 3;
                        } else if (app > 1e-6f && t_ev < t_e) {
                            code = is_ball ? 2 : 4;
                            dteB = (t_ev > __fadd_rn(t_c, 1e-10f)) ? __fsub_rn(t_ev, t_c) : 0.0f;
                            tcn = t_ev;
                        }
                    }
                    int ei = is_ball ? pi : wb;
                    int ej = is_ball ? pj : ww;
                    dI[0] = code; dI[1] = ei; dI[2] = ej;
                    dF[0] = dteB; dF[1] = tcn;
                    if (code != 0) {
                        EvRec er; er.code = code; er.i = ei; er.jw = ej; er.dte = dteB;
                        logp[s].ev[n_ev] = er;   // plain store; ordered by release below
                    }
                }
                __syncthreads();
                int code = dI[0];
                if (code == 0) break;
                int ei = dI[1], ejw = dI[2];
                float dteB = dF[0];
                if (code == 2 || code == 4) blk_integrate(ps, dteB, tid);
                if (code <= 2) {
                    blk_apply_ball(ps, w1, b1s, w2, b2s, w3s, b3s, sc, ei, ejw, tid);
                    vcap = fmaxf(vcap, sc[140]);
                } else {
                    blk_apply_wall(ps, rad, sc, ei, ejw, tid);
                    wallacc += sc[141];
                }
                t_c = dF[1];
                n_ev++;
            }

            if (tid == 0) {
                float fd = (t_e > __fadd_rn(t_c, 1e-10f)) ? __fsub_rn(t_e, t_c) : 0.0f;
                dF[2] = fd;
                logp[s].final_dte = fd;
                logp[s].n_ev = n_ev;
            }
            __syncthreads();
            blk_integrate(ps, dF[2], tid);

            // vmax for next step + reset candidate counter
            {
                float4 P = ps[tid];
                float m2 = P.z * P.z + P.w * P.w;
                #pragma unroll
                for (int off = 32; off; off >>= 1) m2 = fmaxf(m2, __shfl_down(m2, off));
                if ((tid & 63) == 0) redF[tid >> 6] = m2;
                __syncthreads();
                if (tid == 0) {
                    float m = fmaxf(fmaxf(redF[0], redF[1]), fmaxf(redF[2], redF[3]));
                    vmax2bits = __float_as_int(m);
                    candN = 0;
                }
            }

            blk_store_row(out, bf, s + 1, 0, ps, tid);

            // publish step s (release: orders tid0's log writes at agent scope)
            if (tid == 0)
                __hip_atomic_store(done, s + 1, __ATOMIC_RELEASE, __HIP_MEMORY_SCOPE_AGENT);
        }
    } else {
        // ================= consumer: replay the published log =================
        for (int s = 0; s < NS; s++) {
            if (tid == 0) {
                while (__hip_atomic_load(done, __ATOMIC_ACQUIRE, __HIP_MEMORY_SCOPE_AGENT) < s + 1)
                    __builtin_amdgcn_s_sleep(8);
            }
            __syncthreads();
            __builtin_amdgcn_fence(__ATOMIC_ACQUIRE, "agent");

            int ne = logp[s].n_ev;
            float fd = logp[s].final_dte;
            for (int e = 0; e < ne; e++) {
                EvRec er = logp[s].ev[e];
                if (er.code == 2 || er.code == 4) blk_integrate(ps, er.dte, tid);
                if (er.code <= 2) blk_apply_ball(ps, w1, b1s, w2, b2s, w3s, b3s, sc, er.i, er.jw, tid);
                else              blk_apply_wall(ps, rad, sc, er.i, er.jw, tid);
            }
            blk_integrate(ps, fd, tid);
            blk_store_row(out, bf, s + 1, b, ps, tid);
            __syncthreads();
        }
    }
}

extern "C" void kernel_launch(void* const* d_in, const int* in_sizes, int n_in,
                              void* d_out, int out_size, void* d_ws, size_t ws_size,
                              hipStream_t stream) {
    // inputs: 0 state, 1 radii, 2 W1, 3 b1, 4 W2, 5 b2, 6 W3, 7 b3, 8 dt, 9 n_steps
    int* ws = (int*)d_ws;
    sniff_kernel<<<1, 256, 0, stream>>>((const unsigned short*)d_in[0], ws);
    row0_kernel<<<(NBATCH * NB * 4) / 256, 256, 0, stream>>>(d_in[0], d_out, ws);
    fused_kernel<<<NBATCH, 256, 0, stream>>>(
        d_in[0], d_in[1], d_in[2], d_in[3], d_in[4], d_in[5], d_in[6], d_in[7],
        d_in[8], (const int*)d_in[9], d_out, ws);
}

// Round 4
// 9360.553 us; speedup vs baseline: 2.7569x; 1.0429x over previous
//
#include <hip/hip_runtime.h>
#include <stdint.h>

#define NB 256
#define NBATCH 128
#define HID 64
#define MAXEV 5
#define MAXSTEPS 256
#define NT 43          /* 43*6 = 258 >= 256 */
#define NTILES 946     /* 43*44/2 */
#define W2S 65         /* padded LDS stride for W2 rows */
#define CAND_MAX 5120

__device__ __forceinline__ float bf2f(unsigned short u) {
    return __uint_as_float(((unsigned)u) << 16);
}
__device__ __forceinline__ unsigned short f2bf(float f) {
    unsigned u = __float_as_uint(f);
    u += 0x7FFFu + ((u >> 16) & 1u);
    return (unsigned short)(u >> 16);
}
__device__ __forceinline__ float rdin(const void* p, int idx, int bf) {
    return bf ? bf2f(((const unsigned short*)p)[idx]) : ((const float*)p)[idx];
}
__device__ __forceinline__ float silu_f(float x) {
    float s = __fdiv_rn(1.0f, __fadd_rn(1.0f, expf(-x)));
    return __fmul_rn(x, s);
}
__device__ __forceinline__ unsigned long long shfl_down_u64(unsigned long long v, int off) {
    unsigned lo = (unsigned)v, hi = (unsigned)(v >> 32);
    lo = __shfl_down(lo, off);
    hi = __shfl_down(hi, off);
    return (((unsigned long long)hi) << 32) | lo;
}

__device__ void load_weights(float* w1, float* b1s, float* w2, float* b2s, float* w3, float* b3s,
                             const void* W1, const void* B1, const void* W2, const void* B2,
                             const void* W3, const void* B3, int bf, int tid, int nthr) {
    for (int k = tid; k < HID * 2; k += nthr) w1[k] = rdin(W1, k, bf);
    for (int k = tid; k < HID; k += nthr) {
        b1s[k] = rdin(B1, k, bf);
        b2s[k] = rdin(B2, k, bf);
        w3[k]  = rdin(W3, k, bf);
    }
    for (int k = tid; k < HID * HID; k += nthr) {
        int m = k >> 6, c = k & 63;
        w2[m * W2S + c] = rdin(W2, k, bf);
    }
    if (tid == 0) b3s[0] = rdin(B3, 0, bf);
}

// exact-reference pair evaluation; updates min-key kP
__device__ __forceinline__ void pair_min(const float4* ps, int i, int j, unsigned long long& kP) {
    float4 A = ps[i], B = ps[j];
    float dx = __fsub_rn(B.x, A.x), dy = __fsub_rn(B.y, A.y);
    float d2 = __fadd_rn(__fmul_rn(dx, dx), __fmul_rn(dy, dy));
    float p1 = __fmul_rn(__fsub_rn(B.z, A.z), dx);
    float p2 = __fmul_rn(__fsub_rn(B.w, A.w), dy);
    float dot = __fadd_rn(p1, p2);
    float mag = __fadd_rn(fabsf(p1), fabsf(p2));
    bool appr;
    if (fabsf(dot) < __fmul_rn(1e-5f, mag)) {
        float dist = __fsqrt_rn(d2);
        float den = __fadd_rn(dist, 1e-8f);
        float ab = __fadd_rn(__fmul_rn(__fsub_rn(B.z, A.z), __fdiv_rn(dx, den)),
                             __fmul_rn(__fsub_rn(B.w, A.w), __fdiv_rn(dy, den)));
        appr = ab < 0.0f;
    } else {
        appr = dot < 0.0f;
    }
    if (appr) {
        unsigned long long key = (((unsigned long long)__float_as_uint(d2)) << 16) |
                                 (unsigned)((i << 8) | j);
        kP = key < kP ? key : kP;
    }
}

// block-level detect on ps0 (256 threads). Leaders write per-wave minima to redU.
__device__ void blk_detect(const float4* ps, const float* rad,
                           const unsigned* cand, int nc, bool fullscan, int tid,
                           unsigned long long* redU) {
    unsigned long long kP = ~0ull, kW = ~0ull;
    if (fullscan) {
        for (int t = tid; t < NTILES; t += 256) {
            int rem = t, r = 0;
            while (rem >= NT - r) { rem -= NT - r; r++; }
            int i0 = r * 6, j0 = (r + rem) * 6;
            for (int a = 0; a < 6; a++) {
                int i = i0 + a; if (i >= NB) break;
                for (int b = 0; b < 6; b++) {
                    int j = j0 + b;
                    if (j >= NB || j <= i) continue;
                    pair_min(ps, i, j, kP);
                }
            }
        }
    } else {
        for (int c = tid; c < nc; c += 256) {
            unsigned id = cand[c];
            pair_min(ps, (int)(id >> 8), (int)(id & 255u), kP);
        }
    }
    {   // wall candidates: ball = tid, all four walls
        int ball = tid;
        float4 P = ps[ball]; float r = rad[ball];
        #pragma unroll
        for (int w = 0; w < 4; w++) {
            float g; bool valid;
            if (w == 0)      { g = __fsub_rn(P.x, r); valid = P.z < 0.0f; }
            else if (w == 1) { g = __fsub_rn(__fsub_rn(10.0f, P.x), r); valid = P.z > 0.0f; }
            else if (w == 2) { g = __fsub_rn(P.y, r); valid = P.w < 0.0f; }
            else             { g = __fsub_rn(__fsub_rn(10.0f, P.y), r); valid = P.w > 0.0f; }
            if (valid) {
                unsigned gb = __float_as_uint(g);
                unsigned m = (unsigned)(((int)gb) >> 31) | 0x80000000u;
                unsigned sb = gb ^ m;
                unsigned long long key = (((unsigned long long)sb) << 16) |
                                         (unsigned)((ball << 2) | w);
                kW = key < kW ? key : kW;
            }
        }
    }
    #pragma unroll
    for (int off = 32; off; off >>= 1) {
        unsigned long long o1 = shfl_down_u64(kP, off);
        unsigned long long o2 = shfl_down_u64(kW, off);
        kP = o1 < kP ? o1 : kP;
        kW = o2 < kW ? o2 : kW;
    }
    if ((tid & 63) == 0) { redU[tid >> 6] = kP; redU[4 + (tid >> 6)] = kW; }
}

// integrate BOTH sims; one barrier
__device__ __forceinline__ void dual_integrate(float4* ps0, float4* psb, float dte, int tid) {
    float4 P = ps0[tid];
    P.x = __fadd_rn(P.x, __fmul_rn(P.z, dte));
    P.y = __fadd_rn(P.y, __fmul_rn(P.w, dte));
    ps0[tid] = P;
    float4 Q = psb[tid];
    Q.x = __fadd_rn(Q.x, __fmul_rn(Q.z, dte));
    Q.y = __fadd_rn(Q.y, __fmul_rn(Q.w, dte));
    psb[tid] = Q;
    __syncthreads();
}

// dual MLP impulse apply: lanes 0-63 drive sim0 (sc0), lanes 64-127 drive simb (scb).
// sc0[140] <- max new speed of the two balls in sim0 (for fullscan-fallback bound).
__device__ void dual_apply_ball(float4* ps0, float4* psb,
                                const float* w1, const float* b1s, const float* w2,
                                const float* b2s, const float* w3s, const float* b3s,
                                float* sc0, float* scb, int i, int j, int tid) {
    if (tid == 0 || tid == 64) {
        float4* ps = (tid == 0) ? ps0 : psb;
        float*  sc = (tid == 0) ? sc0 : scb;
        float4 A = ps[i], B = ps[j];
        float dx = __fsub_rn(B.x, A.x), dy = __fsub_rn(B.y, A.y);
        float nrm = __fsqrt_rn(__fadd_rn(__fmul_rn(dx, dx), __fmul_rn(dy, dy)));
        float dist = fmaxf(nrm, 1e-8f);
        float nx = __fdiv_rn(dx, dist), ny = __fdiv_rn(dy, dist);
        float dvx = __fsub_rn(B.z, A.z), dvy = __fsub_rn(B.w, A.w);
        float app = __fadd_rn(__fmul_rn(dvx, nx), __fmul_rn(dvy, ny));
        sc[0] = nx; sc[1] = ny; sc[2] = dist; sc[3] = app;
    }
    __syncthreads();
    if (tid < 128) {
        int h = tid & 63;
        float* sc = (tid < 64) ? sc0 : scb;
        float a = __fadd_rn(__fadd_rn(__fmul_rn(sc[2], w1[2 * h]),
                                      __fmul_rn(sc[3], w1[2 * h + 1])), b1s[h]);
        sc[4 + h] = silu_f(a);
    }
    __syncthreads();
    if (tid < 128) {
        int h = tid & 63;
        float* sc = (tid < 64) ? sc0 : scb;
        float acc = 0.0f;
        const float* row = &w2[h * W2S];
        #pragma unroll 8
        for (int k = 0; k < HID; k++) acc = __fadd_rn(acc, __fmul_rn(sc[4 + k], row[k]));
        acc = __fadd_rn(acc, b2s[h]);
        sc[68 + h] = silu_f(acc);
    }
    __syncthreads();
    if (tid == 0 || tid == 64) {
        float4* ps = (tid == 0) ? ps0 : psb;
        float*  sc = (tid == 0) ? sc0 : scb;
        float acc = 0.0f;
        for (int k = 0; k < HID; k++) acc = __fadd_rn(acc, __fmul_rn(sc[68 + k], w3s[k]));
        acc = __fadd_rn(acc, b3s[0]);
        float ix = __fmul_rn(acc, sc[0]), iy = __fmul_rn(acc, sc[1]);
        float4 A = ps[i], B = ps[j];
        A.z = __fadd_rn(A.z, ix);  A.w = __fadd_rn(A.w, iy);
        B.z = __fadd_rn(B.z, -ix); B.w = __fadd_rn(B.w, -iy);
        ps[i] = A; ps[j] = B;
        if (tid == 0) {
            float s1 = sqrtf(A.z * A.z + A.w * A.w);
            float s2 = sqrtf(B.z * B.z + B.w * B.w);
            sc[140] = fmaxf(s1, s2);
        }
    }
    __syncthreads();
}

// dual wall apply: tid0 -> sim0 (pen to sc0[141]), tid64 -> simb
__device__ void dual_apply_wall(float4* ps0, float4* psb, const float* rad,
                                float* sc0, int i, int w, int tid) {
    if (tid == 0 || tid == 64) {
        float4* ps = (tid == 0) ? ps0 : psb;
        const float wnx[4] = {1.f, -1.f, 0.f, 0.f};
        const float wny[4] = {0.f, 0.f, 1.f, -1.f};
        const float wpv[4] = {0.f, -10.f, 0.f, -10.f};
        float4 P = ps[i];
        float vn = __fadd_rn(__fmul_rn(P.z, wnx[w]), __fmul_rn(P.w, wny[w]));
        float t2 = __fmul_rn(2.0f, vn);
        float nvx = __fsub_rn(P.z, __fmul_rn(t2, wnx[w]));
        float nvy = __fsub_rn(P.w, __fmul_rn(t2, wny[w]));
        float pn = __fadd_rn(__fmul_rn(P.x, wnx[w]), __fmul_rn(P.y, wny[w]));
        float pen = fmaxf(__fsub_rn(__fadd_rn(wpv[w], rad[i]), pn), 0.0f);
        float npx = __fadd_rn(P.x, __fmul_rn(pen, wnx[w]));
        float npy = __fadd_rn(P.y, __fmul_rn(pen, wny[w]));
        float4 nP; nP.x = npx; nP.y = npy; nP.z = nvx; nP.w = nvy;
        ps[i] = nP;
        if (tid == 0) sc0[141] = pen;
    }
    __syncthreads();
}

__device__ __forceinline__ void blk_store_row(void* out, int bf, int s1, int b,
                                              const float4* ps, int tid) {
    long long base = ((long long)s1 * NBATCH + b) * (NB * 4);
    float4 P = ps[tid];
    if (bf) {
        ushort4 v;
        v.x = f2bf(P.x); v.y = f2bf(P.y); v.z = f2bf(P.z); v.w = f2bf(P.w);
        ((ushort4*)((unsigned short*)out + base))[tid] = v;
    } else {
        ((float4*)((float*)out + base))[tid] = P;
    }
}

// ---------------- dtype sniffer ----------------
__global__ void sniff_kernel(const unsigned short* st, int* ws) {
    __shared__ int ev;
    if (threadIdx.x == 0) ev = 0;
    __syncthreads();
    unsigned short u = st[threadIdx.x];
    int e = (u >> 7) & 0xFF;
    if (e >= 0x85) atomicOr(&ev, 1);
    __syncthreads();
    if (threadIdx.x == 0) ws[0] = ev ? 0 : 1;   // 1 = bf16, 0 = fp32
}

// ---------------- output row 0 = initial state (bit copy) ----------------
__global__ void row0_kernel(const void* in, void* out, const int* ws) {
    int idx = blockIdx.x * blockDim.x + threadIdx.x;
    if (ws[0]) ((unsigned short*)out)[idx] = ((const unsigned short*)in)[idx];
    else       ((float*)out)[idx] = ((const float*)in)[idx];
}

// ---------------- redundant-producer kernel: every block sims batch 0 + its own batch ----
__global__ __launch_bounds__(256) void sim_kernel(
    const void* in_state, const void* in_rad,
    const void* inW1, const void* inB1, const void* inW2, const void* inB2,
    const void* inW3, const void* inB3, const void* in_dt, const int* in_nsteps,
    void* out, const int* ws) {
    __shared__ float4 ps0[NB];          // batch-0 sim (decision state)
    __shared__ float4 psb[NB];          // own-batch sim
    __shared__ float rad[NB];
    __shared__ float w1[HID * 2], b1s[HID], w2[HID * W2S], b2s[HID], w3s[HID], b3s[1];
    __shared__ float sc0[144], scb[144];
    __shared__ unsigned long long redU[8];
    __shared__ float redF[4];
    __shared__ int dI[4];
    __shared__ float dF[4];
    __shared__ unsigned cand[CAND_MAX];
    __shared__ int candN;
    __shared__ int vmax2bits;

    int tid = threadIdx.x;
    int b = blockIdx.x;
    int bf = ws[0];

    {
        int base0 = tid * 4;
        float4 P;
        P.x = rdin(in_state, base0 + 0, bf);
        P.y = rdin(in_state, base0 + 1, bf);
        P.z = rdin(in_state, base0 + 2, bf);
        P.w = rdin(in_state, base0 + 3, bf);
        ps0[tid] = P;
        int baseb = (b * NB + tid) * 4;
        float4 Q;
        Q.x = rdin(in_state, baseb + 0, bf);
        Q.y = rdin(in_state, baseb + 1, bf);
        Q.z = rdin(in_state, baseb + 2, bf);
        Q.w = rdin(in_state, baseb + 3, bf);
        psb[tid] = Q;
        rad[tid] = rdin(in_rad, tid, bf);
    }
    load_weights(w1, b1s, w2, b2s, w3s, b3s, inW1, inB1, inW2, inB2, inW3, inB3, bf, tid, 256);

    float dtv = rdin(in_dt, 0, bf);
    int NS = in_nsteps[0]; if (NS > MAXSTEPS) NS = MAXSTEPS; if (NS < 0) NS = 0;
    __syncthreads();
    float rsum = __fadd_rn(rad[0], rad[0]);        // radii uniform

    // static tile assignment for candidate build (<=4 tiles/thread)
    int ti0[4], tj0[4], ntile = 0;
    for (int t = tid; t < NTILES; t += 256) {
        int rem = t, r = 0;
        while (rem >= NT - r) { rem -= NT - r; r++; }
        ti0[ntile] = r * 6; tj0[ntile] = (r + rem) * 6; ntile++;
    }

    // initial vmax + candidate counter
    {
        float4 P = ps0[tid];
        float m2 = P.z * P.z + P.w * P.w;
        #pragma unroll
        for (int off = 32; off; off >>= 1) m2 = fmaxf(m2, __shfl_down(m2, off));
        if ((tid & 63) == 0) redF[tid >> 6] = m2;
        __syncthreads();
        if (tid == 0) {
            float m = fmaxf(fmaxf(redF[0], redF[1]), fmaxf(redF[2], redF[3]));
            vmax2bits = __float_as_int(m);
            candN = 0;
        }
    }

    for (int s = 0; s < NS; s++) {
        __syncthreads();   // (A) state + candN + vmax visible
        float vmaxv = sqrtf(fmaxf(__int_as_float(vmax2bits), 0.0f));
        float theta = rsum + 0.05f + 2.0f * dtv * vmaxv + 0.15f;
        float th2 = theta * theta;

        // candidate build on ps0 (distance-only filter)
        for (int t = 0; t < ntile; t++) {
            int i0 = ti0[t], j0 = tj0[t];
            float4 Pi[6], Pj[6];
            #pragma unroll
            for (int a = 0; a < 6; a++) {
                int ii = i0 + a; ii = ii < NB ? ii : NB - 1;
                int jj = j0 + a; jj = jj < NB ? jj : NB - 1;
                Pi[a] = ps0[ii]; Pj[a] = ps0[jj];
            }
            #pragma unroll
            for (int a = 0; a < 6; a++) {
                int i = i0 + a;
                #pragma unroll
                for (int bb = 0; bb < 6; bb++) {
                    int j = j0 + bb;
                    bool ok = (i < NB) && (j < NB) && (j > i);
                    float dx = Pj[bb].x - Pi[a].x;
                    float dy = Pj[bb].y - Pi[a].y;
                    float d2 = dx * dx + dy * dy;
                    if (ok && d2 < th2) {
                        int x = atomicAdd(&candN, 1);
                        if (x < CAND_MAX) cand[x] = (unsigned)((i << 8) | j);
                    }
                }
            }
        }
        __syncthreads();   // (C) candidate list complete

        float t_s = __fmul_rn((float)s, dtv);
        float t_e = __fadd_rn(t_s, dtv);
        float t_c = t_s;
        float vcap = vmaxv;
        float wallacc = 0.0f;
        float margin = 2.0f * dtv * vmaxv + 0.15f;
        int candTotal = candN;
        int nc = candTotal > CAND_MAX ? CAND_MAX : candTotal;

        for (int e = 0; e < MAXEV; e++) {
            bool fullscan = (candTotal > CAND_MAX) ||
                            (2.0f * dtv * vcap + wallacc + 1e-3f > margin);
            blk_detect(ps0, rad, cand, nc, fullscan, tid, redU);
            __syncthreads();
            if (tid == 0) {
                unsigned long long mP = redU[0], mW = redU[4];
                for (int q = 1; q < 4; q++) {
                    mP = redU[q] < mP ? redU[q] : mP;
                    mW = redU[4 + q] < mW ? redU[4 + q] : mW;
                }
                float gball = 1e30f; int pi = 0, pj = 1;
                if (mP != ~0ull) {
                    unsigned id = (unsigned)(mP & 0xFFFFull);
                    pi = id >> 8; pj = id & 255u;
                    float d2 = __uint_as_float((unsigned)(mP >> 16));
                    gball = __fsub_rn(__fsqrt_rn(d2), rsum);
                }
                float gwall = 1e30f; int wb = 0, ww = 0;
                if (mW != ~0ull) {
                    unsigned id = (unsigned)(mW & 0xFFFFull);
                    wb = id >> 2; ww = id & 3u;
                    unsigned sb = (unsigned)(mW >> 16);
                    unsigned gb = (sb & 0x80000000u) ? (sb ^ 0x80000000u) : ~sb;
                    gwall = __uint_as_float(gb);
                }
                bool is_ball = gball <= gwall;
                float gap = is_ball ? gball : gwall;
                int code = 0; float dteB = 0.0f, tcn = t_c;
                if (!(gap > 0.05f)) {
                    float app;
                    if (is_ball) {
                        float4 A = ps0[pi], B = ps0[pj];
                        float dx = __fsub_rn(B.x, A.x), dy = __fsub_rn(B.y, A.y);
                        float nrm = __fsqrt_rn(__fadd_rn(__fmul_rn(dx, dx), __fmul_rn(dy, dy)));
                        float dvx = __fsub_rn(B.z, A.z), dvy = __fsub_rn(B.w, A.w);
                        app = -__fadd_rn(__fdiv_rn(__fmul_rn(dvx, dx), nrm),
                                         __fdiv_rn(__fmul_rn(dvy, dy), nrm));
                    } else {
                        float4 Wb = ps0[wb];
                        app = fabsf(fmaxf(Wb.z, Wb.w));
                    }
                    float t_ev = __fadd_rn(t_c, __fdiv_rn(gap, fmaxf(app, 1e-6f)));
                    if (gap <= 0.0f) {
                        code = is_ball ? 1 : 3;
                    } else if (app > 1e-6f && t_ev < t_e) {
                        code = is_ball ? 2 : 4;
                        dteB = (t_ev > __fadd_rn(t_c, 1e-10f)) ? __fsub_rn(t_ev, t_c) : 0.0f;
                        tcn = t_ev;
                    }
                }
                dI[0] = code;
                dI[1] = is_ball ? pi : wb;
                dI[2] = is_ball ? pj : ww;
                dF[0] = dteB; dF[1] = tcn;
            }
            __syncthreads();
            int code = dI[0];
            if (code == 0) break;
            int ei = dI[1], ejw = dI[2];
            float dteB = dF[0];
            if (code == 2 || code == 4) dual_integrate(ps0, psb, dteB, tid);
            if (code <= 2) {
                dual_apply_ball(ps0, psb, w1, b1s, w2, b2s, w3s, b3s, sc0, scb, ei, ejw, tid);
                vcap = fmaxf(vcap, sc0[140]);
            } else {
                dual_apply_wall(ps0, psb, rad, sc0, ei, ejw, tid);
                wallacc += sc0[141];
            }
            t_c = dF[1];
        }

        if (tid == 0) {
            float fd = (t_e > __fadd_rn(t_c, 1e-10f)) ? __fsub_rn(t_e, t_c) : 0.0f;
            dF[2] = fd;
        }
        __syncthreads();
        dual_integrate(ps0, psb, dF[2], tid);

        // vmax for next step + reset candidate counter (on ps0)
        {
            float4 P = ps0[tid];
            float m2 = P.z * P.z + P.w * P.w;
            #pragma unroll
            for (int off = 32; off; off >>= 1) m2 = fmaxf(m2, __shfl_down(m2, off));
            if ((tid & 63) == 0) redF[tid >> 6] = m2;
            __syncthreads();
            if (tid == 0) {
                float m = fmaxf(fmaxf(redF[0], redF[1]), fmaxf(redF[2], redF[3]));
                vmax2bits = __float_as_int(m);
                candN = 0;
            }
        }

        blk_store_row(out, bf, s + 1, b, psb, tid);
    }
}

extern "C" void kernel_launch(void* const* d_in, const int* in_sizes, int n_in,
                              void* d_out, int out_size, void* d_ws, size_t ws_size,
                              hipStream_t stream) {
    // inputs: 0 state, 1 radii, 2 W1, 3 b1, 4 W2, 5 b2, 6 W3, 7 b3, 8 dt, 9 n_steps
    int* ws = (int*)d_ws;
    sniff_kernel<<<1, 256, 0, stream>>>((const unsigned short*)d_in[0], ws);
    row0_kernel<<<(NBATCH * NB * 4) / 256, 256, 0, stream>>>(d_in[0], d_out, ws);
    sim_kernel<<<NBATCH, 256, 0, stream>>>(
        d_in[0], d_in[1], d_in[2], d_in[3], d_in[4], d_in[5], d_in[6], d_in[7],
        d_in[8], (const int*)d_in[9], d_out, ws);
}

// Round 6
// 5641.117 us; speedup vs baseline: 4.5747x; 1.6593x over previous
//
#include <hip/hip_runtime.h>
#include <stdint.h>

#define NB 256
#define NBATCH 128
#define HID 64
#define MAXEV 5
#define MAXSTEPS 256
#define NT 43          /* 43*6 = 258 >= 256 */
#define NTILES 946     /* 43*44/2 */
#define W2S 65         /* padded LDS stride for W2 rows */
#define CAND_MAX 5120

__device__ __forceinline__ float bf2f(unsigned short u) {
    return __uint_as_float(((unsigned)u) << 16);
}
__device__ __forceinline__ unsigned short f2bf(float f) {
    unsigned u = __float_as_uint(f);
    u += 0x7FFFu + ((u >> 16) & 1u);
    return (unsigned short)(u >> 16);
}
__device__ __forceinline__ float rdin(const void* p, int idx, int bf) {
    return bf ? bf2f(((const unsigned short*)p)[idx]) : ((const float*)p)[idx];
}
__device__ __forceinline__ float silu_f(float x) {
    float s = __fdiv_rn(1.0f, __fadd_rn(1.0f, expf(-x)));
    return __fmul_rn(x, s);
}
__device__ __forceinline__ unsigned long long shfl_down_u64(unsigned long long v, int off) {
    unsigned lo = (unsigned)v, hi = (unsigned)(v >> 32);
    lo = __shfl_down(lo, off);
    hi = __shfl_down(hi, off);
    return (((unsigned long long)hi) << 32) | lo;
}

__device__ void load_weights(float* w1, float* b1s, float* w2, float* b2s, float* w3, float* b3s,
                             const void* W1, const void* B1, const void* W2, const void* B2,
                             const void* W3, const void* B3, int bf, int tid, int nthr) {
    for (int k = tid; k < HID * 2; k += nthr) w1[k] = rdin(W1, k, bf);
    for (int k = tid; k < HID; k += nthr) {
        b1s[k] = rdin(B1, k, bf);
        b2s[k] = rdin(B2, k, bf);
        w3[k]  = rdin(W3, k, bf);
    }
    for (int k = tid; k < HID * HID; k += nthr) {
        int m = k >> 6, c = k & 63;
        w2[m * W2S + c] = rdin(W2, k, bf);
    }
    if (tid == 0) b3s[0] = rdin(B3, 0, bf);
}

// exact-reference pair evaluation; updates min-key kP
__device__ __forceinline__ void pair_min(const float4* ps, int i, int j, unsigned long long& kP) {
    float4 A = ps[i], B = ps[j];
    float dx = __fsub_rn(B.x, A.x), dy = __fsub_rn(B.y, A.y);
    float d2 = __fadd_rn(__fmul_rn(dx, dx), __fmul_rn(dy, dy));
    float p1 = __fmul_rn(__fsub_rn(B.z, A.z), dx);
    float p2 = __fmul_rn(__fsub_rn(B.w, A.w), dy);
    float dot = __fadd_rn(p1, p2);
    float mag = __fadd_rn(fabsf(p1), fabsf(p2));
    bool appr;
    if (fabsf(dot) < __fmul_rn(1e-5f, mag)) {
        float dist = __fsqrt_rn(d2);
        float den = __fadd_rn(dist, 1e-8f);
        float ab = __fadd_rn(__fmul_rn(__fsub_rn(B.z, A.z), __fdiv_rn(dx, den)),
                             __fmul_rn(__fsub_rn(B.w, A.w), __fdiv_rn(dy, den)));
        appr = ab < 0.0f;
    } else {
        appr = dot < 0.0f;
    }
    if (appr) {
        unsigned long long key = (((unsigned long long)__float_as_uint(d2)) << 16) |
                                 (unsigned)((i << 8) | j);
        kP = key < kP ? key : kP;
    }
}

// ---------------- dtype sniffer ----------------
__global__ void sniff_kernel(const unsigned short* st, int* ws) {
    __shared__ int ev;
    if (threadIdx.x == 0) ev = 0;
    __syncthreads();
    unsigned short u = st[threadIdx.x];
    int e = (u >> 7) & 0xFF;
    if (e >= 0x85) atomicOr(&ev, 1);
    __syncthreads();
    if (threadIdx.x == 0) ws[0] = ev ? 0 : 1;   // 1 = bf16, 0 = fp32
}

// ---------------- output row 0 = initial state (bit copy) ----------------
__global__ void row0_kernel(const void* in, void* out, const int* ws) {
    int idx = blockIdx.x * blockDim.x + threadIdx.x;
    if (ws[0]) ((unsigned short*)out)[idx] = ((const unsigned short*)in)[idx];
    else       ((float*)out)[idx] = ((const float*)in)[idx];
}

// ---------------- redundant-producer, 1024-thread, phase-minimized ----------------
__global__ __launch_bounds__(1024, 1) void sim_kernel(
    const void* in_state, const void* in_rad,
    const void* inW1, const void* inB1, const void* inW2, const void* inB2,
    const void* inW3, const void* inB3, const void* in_dt, const int* in_nsteps,
    void* out, const int* ws) {
    __shared__ float4 ps0[NB];          // batch-0 sim (decision state)
    __shared__ float4 psb[NB];          // own-batch sim
    __shared__ float rad[NB];
    __shared__ float w1[HID * 2], b1s[HID], w2[HID * W2S], b2s[HID], w3s[HID], b3s[1];
    // sc layout: [0..3] nx,ny,dist,app  [4..67] h1  [68..131] h2  [132..135] saved A.z,A.w,B.z,B.w
    __shared__ float sc0[136], scb[136];
    __shared__ unsigned long long redP[16], redW[16];
    __shared__ float redF[4];
    __shared__ unsigned cand[CAND_MAX];
    __shared__ int candN;

    int tid = threadIdx.x;
    int b = blockIdx.x;
    int bf = ws[0];

    if (tid < NB) {
        int base0 = tid * 4;
        float4 P;
        P.x = rdin(in_state, base0 + 0, bf);
        P.y = rdin(in_state, base0 + 1, bf);
        P.z = rdin(in_state, base0 + 2, bf);
        P.w = rdin(in_state, base0 + 3, bf);
        ps0[tid] = P;
        int baseb = (b * NB + tid) * 4;
        float4 Q;
        Q.x = rdin(in_state, baseb + 0, bf);
        Q.y = rdin(in_state, baseb + 1, bf);
        Q.z = rdin(in_state, baseb + 2, bf);
        Q.w = rdin(in_state, baseb + 3, bf);
        psb[tid] = Q;
        rad[tid] = rdin(in_rad, tid, bf);
        // initial vmax reduce (velocity magnitude² of batch-0 ball)
        float m2 = P.z * P.z + P.w * P.w;
        #pragma unroll
        for (int off = 32; off; off >>= 1) m2 = fmaxf(m2, __shfl_down(m2, off));
        if ((tid & 63) == 0) redF[tid >> 6] = m2;
    }
    load_weights(w1, b1s, w2, b2s, w3s, b3s, inW1, inB1, inW2, inB2, inW3, inB3, bf, tid, 1024);
    if (tid == 0) candN = 0;

    float dtv = rdin(in_dt, 0, bf);
    int NS = in_nsteps[0]; if (NS > MAXSTEPS) NS = MAXSTEPS; if (NS < 0) NS = 0;

    // static tile assignment (one 6x6 tile per thread, tids 0..945)
    int myI0 = -1, myJ0 = 0;
    if (tid < NTILES) {
        int rem = tid, r = 0;
        while (rem >= NT - r) { rem -= NT - r; r++; }
        myI0 = r * 6; myJ0 = (r + rem) * 6;
    }
    __syncthreads();
    float rsum = __fadd_rn(rad[0], rad[0]);        // radii uniform

    int nc = 0;
    bool candOvf = false;

    for (int s = 0; s < NS; s++) {
        float vmaxv = sqrtf(fmaxf(fmaxf(redF[0], redF[1]), fmaxf(redF[2], redF[3])));
        float theta = rsum + 0.05f + 2.0f * dtv * vmaxv + 0.15f;
        float th2 = theta * theta;
        float t_s = __fmul_rn((float)s, dtv);
        float t_e = __fadd_rn(t_s, dtv);
        float t_c = t_s;
        float vcap = vmaxv;
        float wallacc = 0.0f;
        float margin = 2.0f * dtv * vmaxv + 0.15f;

        for (int e = 0; e < MAXEV; e++) {
            // ---------- detect phase ----------
            unsigned long long kP = ~0ull, kW = ~0ull;
            bool fullscan = (e == 0) || candOvf ||
                            (2.0f * dtv * vcap + wallacc + 1e-3f > margin);
            bool doAppend = (e == 0);
            if (fullscan) {
                if (myI0 >= 0) {
                    float4 Pi[6], Pj[6];
                    #pragma unroll
                    for (int a = 0; a < 6; a++) {
                        int ii = myI0 + a; ii = ii < NB ? ii : NB - 1;
                        int jj = myJ0 + a; jj = jj < NB ? jj : NB - 1;
                        Pi[a] = ps0[ii]; Pj[a] = ps0[jj];
                    }
                    #pragma unroll
                    for (int a = 0; a < 6; a++) {
                        int i = myI0 + a;
                        #pragma unroll
                        for (int bb = 0; bb < 6; bb++) {
                            int j = myJ0 + bb;
                            bool ok = (i < NB) && (j < NB) && (j > i);
                            float dx = __fsub_rn(Pj[bb].x, Pi[a].x);
                            float dy = __fsub_rn(Pj[bb].y, Pi[a].y);
                            float d2 = __fadd_rn(__fmul_rn(dx, dx), __fmul_rn(dy, dy));
                            float p1 = __fmul_rn(__fsub_rn(Pj[bb].z, Pi[a].z), dx);
                            float p2 = __fmul_rn(__fsub_rn(Pj[bb].w, Pi[a].w), dy);
                            float dot = __fadd_rn(p1, p2);
                            float mag = __fadd_rn(fabsf(p1), fabsf(p2));
                            bool appr;
                            if (fabsf(dot) < __fmul_rn(1e-5f, mag)) {
                                float dist = __fsqrt_rn(d2);
                                float den = __fadd_rn(dist, 1e-8f);
                                float ab = __fadd_rn(
                                    __fmul_rn(__fsub_rn(Pj[bb].z, Pi[a].z), __fdiv_rn(dx, den)),
                                    __fmul_rn(__fsub_rn(Pj[bb].w, Pi[a].w), __fdiv_rn(dy, den)));
                                appr = ab < 0.0f;
                            } else {
                                appr = dot < 0.0f;
                            }
                            if (ok && appr) {
                                unsigned long long key =
                                    (((unsigned long long)__float_as_uint(d2)) << 16) |
                                    (unsigned)((i << 8) | j);
                                kP = key < kP ? key : kP;
                            }
                            if (doAppend && ok && d2 < th2) {
                                int x = atomicAdd(&candN, 1);
                                if (x < CAND_MAX) cand[x] = (unsigned)((i << 8) | j);
                            }
                        }
                    }
                }
            } else {
                for (int c = tid; c < nc; c += 1024) {
                    unsigned id = cand[c];
                    pair_min(ps0, (int)(id >> 8), (int)(id & 255u), kP);
                }
            }
            {   // wall candidate: exactly one per thread (tid = ball*4+w)
                int ball = tid >> 2, w = tid & 3;
                float4 P = ps0[ball]; float r = rad[ball];
                float g; bool valid;
                if (w == 0)      { g = __fsub_rn(P.x, r); valid = P.z < 0.0f; }
                else if (w == 1) { g = __fsub_rn(__fsub_rn(10.0f, P.x), r); valid = P.z > 0.0f; }
                else if (w == 2) { g = __fsub_rn(P.y, r); valid = P.w < 0.0f; }
                else             { g = __fsub_rn(__fsub_rn(10.0f, P.y), r); valid = P.w > 0.0f; }
                if (valid) {
                    unsigned gb = __float_as_uint(g);
                    unsigned m = (unsigned)(((int)gb) >> 31) | 0x80000000u;
                    unsigned sb = gb ^ m;
                    unsigned long long key = (((unsigned long long)sb) << 16) | (unsigned)tid;
                    kW = key < kW ? key : kW;
                }
            }
            #pragma unroll
            for (int off = 32; off; off >>= 1) {
                unsigned long long o1 = shfl_down_u64(kP, off);
                unsigned long long o2 = shfl_down_u64(kW, off);
                kP = o1 < kP ? o1 : kP;
                kW = o2 < kW ? o2 : kW;
            }
            if ((tid & 63) == 0) { redP[tid >> 6] = kP; redW[tid >> 6] = kW; }
            __syncthreads();                                     // B1

            if (e == 0) {
                int ct = candN;
                candOvf = ct > CAND_MAX;
                nc = candOvf ? CAND_MAX : ct;
            }

            // ---------- decision (computed redundantly by ALL threads) ----------
            unsigned long long mP = redP[0], mW = redW[0];
            #pragma unroll
            for (int q = 1; q < 16; q++) {
                mP = redP[q] < mP ? redP[q] : mP;
                mW = redW[q] < mW ? redW[q] : mW;
            }
            float gball = 1e30f; int pi = 0, pj = 1;
            if (mP != ~0ull) {
                unsigned id = (unsigned)(mP & 0xFFFFull);
                pi = id >> 8; pj = id & 255u;
                float d2 = __uint_as_float((unsigned)(mP >> 16));
                gball = __fsub_rn(__fsqrt_rn(d2), rsum);
            }
            float gwall = 1e30f; int wb = 0, ww = 0;
            if (mW != ~0ull) {
                unsigned id = (unsigned)(mW & 0xFFFFull);
                wb = id >> 2; ww = id & 3u;
                unsigned sb = (unsigned)(mW >> 16);
                unsigned gb = (sb & 0x80000000u) ? (sb ^ 0x80000000u) : ~sb;
                gwall = __uint_as_float(gb);
            }
            bool is_ball = gball <= gwall;
            float gap = is_ball ? gball : gwall;
            int code = 0; float dteB = 0.0f, tcn = t_c;
            if (!(gap > 0.05f)) {
                float app;
                if (is_ball) {
                    float4 A = ps0[pi], B = ps0[pj];
                    float dx = __fsub_rn(B.x, A.x), dy = __fsub_rn(B.y, A.y);
                    float nrm = __fsqrt_rn(__fadd_rn(__fmul_rn(dx, dx), __fmul_rn(dy, dy)));
                    float dvx = __fsub_rn(B.z, A.z), dvy = __fsub_rn(B.w, A.w);
                    app = -__fadd_rn(__fdiv_rn(__fmul_rn(dvx, dx), nrm),
                                     __fdiv_rn(__fmul_rn(dvy, dy), nrm));
                } else {
                    float4 Wb = ps0[wb];
                    app = fabsf(fmaxf(Wb.z, Wb.w));
                }
                float t_ev = __fadd_rn(t_c, __fdiv_rn(gap, fmaxf(app, 1e-6f)));
                if (gap <= 0.0f) {
                    code = is_ball ? 1 : 3;
                } else if (app > 1e-6f && t_ev < t_e) {
                    code = is_ball ? 2 : 4;
                    dteB = (t_ev > __fadd_rn(t_c, 1e-10f)) ? __fsub_rn(t_ev, t_c) : 0.0f;
                    tcn = t_ev;
                }
            }
            if (code == 0) break;
            int ei = is_ball ? pi : wb;
            int ejw = is_ball ? pj : ww;
            bool integ = (code == 2) || (code == 4);

            // B1b: all decision reads of ps0 complete before any apply-phase write.
            __syncthreads();

            if (code <= 2) {
                // ---------- ball event ----------
                // phase G: bulk integrate (excluding ei,ejw) + leaders do i,j + geometry
                if (tid < NB) {
                    if (integ && tid != ei && tid != ejw) {
                        float4 P = ps0[tid];
                        P.x = __fadd_rn(P.x, __fmul_rn(P.z, dteB));
                        P.y = __fadd_rn(P.y, __fmul_rn(P.w, dteB));
                        ps0[tid] = P;
                    }
                } else if (tid < 2 * NB) {
                    int t = tid - NB;
                    if (integ && t != ei && t != ejw) {
                        float4 Q = psb[t];
                        Q.x = __fadd_rn(Q.x, __fmul_rn(Q.z, dteB));
                        Q.y = __fadd_rn(Q.y, __fmul_rn(Q.w, dteB));
                        psb[t] = Q;
                    }
                }
                if (tid == 0 || tid == 64) {
                    float4* ps = (tid == 0) ? ps0 : psb;
                    float*  sc = (tid == 0) ? sc0 : scb;
                    float4 A = ps[ei], B = ps[ejw];
                    if (integ) {
                        A.x = __fadd_rn(A.x, __fmul_rn(A.z, dteB));
                        A.y = __fadd_rn(A.y, __fmul_rn(A.w, dteB));
                        B.x = __fadd_rn(B.x, __fmul_rn(B.z, dteB));
                        B.y = __fadd_rn(B.y, __fmul_rn(B.w, dteB));
                        ps[ei] = A; ps[ejw] = B;
                    }
                    float dx = __fsub_rn(B.x, A.x), dy = __fsub_rn(B.y, A.y);
                    float nrm = __fsqrt_rn(__fadd_rn(__fmul_rn(dx, dx), __fmul_rn(dy, dy)));
                    float dist = fmaxf(nrm, 1e-8f);
                    float nx = __fdiv_rn(dx, dist), ny = __fdiv_rn(dy, dist);
                    float dvx = __fsub_rn(B.z, A.z), dvy = __fsub_rn(B.w, A.w);
                    float app2 = __fadd_rn(__fmul_rn(dvx, nx), __fmul_rn(dvy, ny));
                    sc[0] = nx; sc[1] = ny; sc[2] = dist; sc[3] = app2;
                    sc[132] = A.z; sc[133] = A.w; sc[134] = B.z; sc[135] = B.w;
                }
                __syncthreads();                                 // B2
                if (tid < 128) {
                    int h = tid & 63;
                    float* sc = (tid < 64) ? sc0 : scb;
                    float a = __fadd_rn(__fadd_rn(__fmul_rn(sc[2], w1[2 * h]),
                                                  __fmul_rn(sc[3], w1[2 * h + 1])), b1s[h]);
                    sc[4 + h] = silu_f(a);
                }
                __syncthreads();                                 // B3
                if (tid < 128) {
                    int h = tid & 63;
                    float* sc = (tid < 64) ? sc0 : scb;
                    float acc = 0.0f;
                    const float* row = &w2[h * W2S];
                    #pragma unroll 8
                    for (int k = 0; k < HID; k++) acc = __fadd_rn(acc, __fmul_rn(sc[4 + k], row[k]));
                    acc = __fadd_rn(acc, b2s[h]);
                    sc[68 + h] = silu_f(acc);
                }
                __syncthreads();                                 // B4
                // phase L3: all threads compute sim0 impulse (for vcap); leaders write vels
                {
                    float acc = 0.0f;
                    for (int k = 0; k < HID; k++)
                        acc = __fadd_rn(acc, __fmul_rn(sc0[68 + k], w3s[k]));
                    float impv = __fadd_rn(acc, b3s[0]);
                    float ix = __fmul_rn(impv, sc0[0]), iy = __fmul_rn(impv, sc0[1]);
                    float nAz = __fadd_rn(sc0[132], ix),  nAw = __fadd_rn(sc0[133], iy);
                    float nBz = __fadd_rn(sc0[134], -ix), nBw = __fadd_rn(sc0[135], -iy);
                    if (tid == 0) {
                        ps0[ei].z = nAz;  ps0[ei].w = nAw;
                        ps0[ejw].z = nBz; ps0[ejw].w = nBw;
                    }
                    float s1 = sqrtf(nAz * nAz + nAw * nAw);
                    float s2 = sqrtf(nBz * nBz + nBw * nBw);
                    vcap = fmaxf(vcap, fmaxf(s1, s2));
                    if (tid == 64) {
                        float accB = 0.0f;
                        for (int k = 0; k < HID; k++)
                            accB = __fadd_rn(accB, __fmul_rn(scb[68 + k], w3s[k]));
                        float impb = __fadd_rn(accB, b3s[0]);
                        float ixb = __fmul_rn(impb, scb[0]), iyb = __fmul_rn(impb, scb[1]);
                        psb[ei].z = __fadd_rn(scb[132], ixb);
                        psb[ei].w = __fadd_rn(scb[133], iyb);
                        psb[ejw].z = __fadd_rn(scb[134], -ixb);
                        psb[ejw].w = __fadd_rn(scb[135], -iyb);
                    }
                }
                __syncthreads();                                 // B5
            } else {
                // ---------- wall event ----------
                // phase W1: bulk integrate (excluding ei) + all compute wall result
                if (tid < NB) {
                    if (integ && tid != ei) {
                        float4 P = ps0[tid];
                        P.x = __fadd_rn(P.x, __fmul_rn(P.z, dteB));
                        P.y = __fadd_rn(P.y, __fmul_rn(P.w, dteB));
                        ps0[tid] = P;
                    }
                } else if (tid < 2 * NB) {
                    int t = tid - NB;
                    if (integ && t != ei) {
                        float4 Q = psb[t];
                        Q.x = __fadd_rn(Q.x, __fmul_rn(Q.z, dteB));
                        Q.y = __fadd_rn(Q.y, __fmul_rn(Q.w, dteB));
                        psb[t] = Q;
                    }
                }
                const float wnx[4] = {1.f, -1.f, 0.f, 0.f};
                const float wny[4] = {0.f, 0.f, 1.f, -1.f};
                const float wpv[4] = {0.f, -10.f, 0.f, -10.f};
                int w = ejw;
                float4 nP0;
                {
                    float4 P = ps0[ei];
                    if (integ) {
                        P.x = __fadd_rn(P.x, __fmul_rn(P.z, dteB));
                        P.y = __fadd_rn(P.y, __fmul_rn(P.w, dteB));
                    }
                    float vn = __fadd_rn(__fmul_rn(P.z, wnx[w]), __fmul_rn(P.w, wny[w]));
                    float t2 = __fmul_rn(2.0f, vn);
                    float nvx = __fsub_rn(P.z, __fmul_rn(t2, wnx[w]));
                    float nvy = __fsub_rn(P.w, __fmul_rn(t2, wny[w]));
                    float pn = __fadd_rn(__fmul_rn(P.x, wnx[w]), __fmul_rn(P.y, wny[w]));
                    float pen = fmaxf(__fsub_rn(__fadd_rn(wpv[w], rad[ei]), pn), 0.0f);
                    nP0.x = __fadd_rn(P.x, __fmul_rn(pen, wnx[w]));
                    nP0.y = __fadd_rn(P.y, __fmul_rn(pen, wny[w]));
                    nP0.z = nvx; nP0.w = nvy;
                    wallacc += pen;
                }
                float4 nPb;
                if (tid == 64) {
                    float4 P = psb[ei];
                    if (integ) {
                        P.x = __fadd_rn(P.x, __fmul_rn(P.z, dteB));
                        P.y = __fadd_rn(P.y, __fmul_rn(P.w, dteB));
                    }
                    float vn = __fadd_rn(__fmul_rn(P.z, wnx[w]), __fmul_rn(P.w, wny[w]));
                    float t2 = __fmul_rn(2.0f, vn);
                    float nvx = __fsub_rn(P.z, __fmul_rn(t2, wnx[w]));
                    float nvy = __fsub_rn(P.w, __fmul_rn(t2, wny[w]));
                    float pn = __fadd_rn(__fmul_rn(P.x, wnx[w]), __fmul_rn(P.y, wny[w]));
                    float pen = fmaxf(__fsub_rn(__fadd_rn(wpv[w], rad[ei]), pn), 0.0f);
                    nPb.x = __fadd_rn(P.x, __fmul_rn(pen, wnx[w]));
                    nPb.y = __fadd_rn(P.y, __fmul_rn(pen, wny[w]));
                    nPb.z = nvx; nPb.w = nvy;
                }
                __syncthreads();                                 // B2w (reads done)
                if (tid == 0)  ps0[ei] = nP0;
                if (tid == 64) psb[ei] = nPb;
                __syncthreads();                                 // B3w
            }
            t_c = tcn;
        }

        // ---------- step end: final integrate + vmax + store (fused) ----------
        float fd = (t_e > __fadd_rn(t_c, 1e-10f)) ? __fsub_rn(t_e, t_c) : 0.0f;
        if (tid < NB) {
            float4 P = ps0[tid];
            P.x = __fadd_rn(P.x, __fmul_rn(P.z, fd));
            P.y = __fadd_rn(P.y, __fmul_rn(P.w, fd));
            ps0[tid] = P;
            float m2 = P.z * P.z + P.w * P.w;
            #pragma unroll
            for (int off = 32; off; off >>= 1) m2 = fmaxf(m2, __shfl_down(m2, off));
            if ((tid & 63) == 0) redF[tid >> 6] = m2;
            if (tid == 0) candN = 0;
        } else if (tid < 2 * NB) {
            int t = tid - NB;
            float4 Q = psb[t];
            Q.x = __fadd_rn(Q.x, __fmul_rn(Q.z, fd));
            Q.y = __fadd_rn(Q.y, __fmul_rn(Q.w, fd));
            psb[t] = Q;
            long long base = ((long long)(s + 1) * NBATCH + b) * (NB * 4);
            if (bf) {
                ushort4 v;
                v.x = f2bf(Q.x); v.y = f2bf(Q.y); v.z = f2bf(Q.z); v.w = f2bf(Q.w);
                ((ushort4*)((unsigned short*)out + base))[t] = v;
            } else {
                ((float4*)((float*)out + base))[t] = Q;
            }
        }
        __syncthreads();
    }
}

extern "C" void kernel_launch(void* const* d_in, const int* in_sizes, int n_in,
                              void* d_out, int out_size, void* d_ws, size_t ws_size,
                              hipStream_t stream) {
    // inputs: 0 state, 1 radii, 2 W1, 3 b1, 4 W2, 5 b2, 6 W3, 7 b3, 8 dt, 9 n_steps
    int* ws = (int*)d_ws;
    sniff_kernel<<<1, 256, 0, stream>>>((const unsigned short*)d_in[0], ws);
    row0_kernel<<<(NBATCH * NB * 4) / 256, 256, 0, stream>>>(d_in[0], d_out, ws);
    sim_kernel<<<NBATCH, 1024, 0, stream>>>(
        d_in[0], d_in[1], d_in[2], d_in[3], d_in[4], d_in[5], d_in[6], d_in[7],
        d_in[8], (const int*)d_in[9], d_out, ws);
}

// Round 7
// 4851.055 us; speedup vs baseline: 5.3197x; 1.1629x over previous
//
#include <hip/hip_runtime.h>
#include <stdint.h>

#define NB 256
#define NBATCH 128
#define HID 64
#define MAXEV 5
#define MAXSTEPS 256
#define NT 43          /* 43*6 = 258 >= 256 */
#define NTILES 946     /* 43*44/2 */
#define W2S 65         /* padded LDS stride for W2 rows */
#define CAND_MAX 5120

__device__ __forceinline__ float bf2f(unsigned short u) {
    return __uint_as_float(((unsigned)u) << 16);
}
__device__ __forceinline__ unsigned short f2bf(float f) {
    unsigned u = __float_as_uint(f);
    u += 0x7FFFu + ((u >> 16) & 1u);
    return (unsigned short)(u >> 16);
}
__device__ __forceinline__ float rdin(const void* p, int idx, int bf) {
    return bf ? bf2f(((const unsigned short*)p)[idx]) : ((const float*)p)[idx];
}
__device__ __forceinline__ float silu_f(float x) {
    float s = __fdiv_rn(1.0f, __fadd_rn(1.0f, expf(-x)));
    return __fmul_rn(x, s);
}
__device__ __forceinline__ void lds_fence() {   // in-wave LDS round-trip ordering
    __builtin_amdgcn_wave_barrier();
    __threadfence_block();
    __builtin_amdgcn_wave_barrier();
}
__device__ __forceinline__ unsigned long long shfl_down_u64(unsigned long long v, int off) {
    unsigned lo = (unsigned)v, hi = (unsigned)(v >> 32);
    lo = __shfl_down(lo, off);
    hi = __shfl_down(hi, off);
    return (((unsigned long long)hi) << 32) | lo;
}

__device__ void load_weights(float* w1, float* b1s, float* w2, float* b2s, float* w3, float* b3s,
                             const void* W1, const void* B1, const void* W2, const void* B2,
                             const void* W3, const void* B3, int bf, int tid, int nthr) {
    for (int k = tid; k < HID * 2; k += nthr) w1[k] = rdin(W1, k, bf);
    for (int k = tid; k < HID; k += nthr) {
        b1s[k] = rdin(B1, k, bf);
        b2s[k] = rdin(B2, k, bf);
        w3[k]  = rdin(W3, k, bf);
    }
    for (int k = tid; k < HID * HID; k += nthr) {
        int m = k >> 6, c = k & 63;
        w2[m * W2S + c] = rdin(W2, k, bf);
    }
    if (tid == 0) b3s[0] = rdin(B3, 0, bf);
}

// exact-reference pair evaluation; updates min-key kP
__device__ __forceinline__ void pair_min(const float4* ps, int i, int j, unsigned long long& kP) {
    float4 A = ps[i], B = ps[j];
    float dx = __fsub_rn(B.x, A.x), dy = __fsub_rn(B.y, A.y);
    float d2 = __fadd_rn(__fmul_rn(dx, dx), __fmul_rn(dy, dy));
    float p1 = __fmul_rn(__fsub_rn(B.z, A.z), dx);
    float p2 = __fmul_rn(__fsub_rn(B.w, A.w), dy);
    float dot = __fadd_rn(p1, p2);
    float mag = __fadd_rn(fabsf(p1), fabsf(p2));
    bool appr;
    if (fabsf(dot) < __fmul_rn(1e-5f, mag)) {
        float dist = __fsqrt_rn(d2);
        float den = __fadd_rn(dist, 1e-8f);
        float ab = __fadd_rn(__fmul_rn(__fsub_rn(B.z, A.z), __fdiv_rn(dx, den)),
                             __fmul_rn(__fsub_rn(B.w, A.w), __fdiv_rn(dy, den)));
        appr = ab < 0.0f;
    } else {
        appr = dot < 0.0f;
    }
    if (appr) {
        unsigned long long key = (((unsigned long long)__float_as_uint(d2)) << 16) |
                                 (unsigned)((i << 8) | j);
        kP = key < kP ? key : kP;
    }
}

// ---------------- dtype sniffer ----------------
__global__ void sniff_kernel(const unsigned short* st, int* ws) {
    __shared__ int ev;
    if (threadIdx.x == 0) ev = 0;
    __syncthreads();
    unsigned short u = st[threadIdx.x];
    int e = (u >> 7) & 0xFF;
    if (e >= 0x85) atomicOr(&ev, 1);
    __syncthreads();
    if (threadIdx.x == 0) ws[0] = ev ? 0 : 1;   // 1 = bf16, 0 = fp32
}

// ---------------- output row 0 = initial state (bit copy) ----------------
__global__ void row0_kernel(const void* in, void* out, const int* ws) {
    int idx = blockIdx.x * blockDim.x + threadIdx.x;
    if (ws[0]) ((unsigned short*)out)[idx] = ((const unsigned short*)in)[idx];
    else       ((float*)out)[idx] = ((const float*)in)[idx];
}

// ------- redundant-producer, wave0-decision, 3-barrier event loop -------
__global__ __launch_bounds__(1024, 1) void sim_kernel(
    const void* in_state, const void* in_rad,
    const void* inW1, const void* inB1, const void* inW2, const void* inB2,
    const void* inW3, const void* inB3, const void* in_dt, const int* in_nsteps,
    void* out, const int* ws) {
    __shared__ float4 ps0[NB];          // batch-0 sim (decision state)
    __shared__ float4 psb[NB];          // own-batch sim
    __shared__ float rad[NB];
    __shared__ float w1[HID * 2], b1s[HID], w2[HID * W2S], b2s[HID], w3s[HID], b3s[1];
    __shared__ float sc0[132], scb[132];      // [4..67] h1, [68..131] h2
    __shared__ unsigned long long redP[16], redW[16];
    __shared__ float redF[4];
    __shared__ unsigned cand[CAND_MAX];
    __shared__ int candN;
    __shared__ int dI[4];
    __shared__ float dF[4];
    __shared__ int candF;

    int tid = threadIdx.x;
    int b = blockIdx.x;
    int bf = ws[0];

    if (tid < NB) {
        int base0 = tid * 4;
        float4 P;
        P.x = rdin(in_state, base0 + 0, bf);
        P.y = rdin(in_state, base0 + 1, bf);
        P.z = rdin(in_state, base0 + 2, bf);
        P.w = rdin(in_state, base0 + 3, bf);
        ps0[tid] = P;
        int baseb = (b * NB + tid) * 4;
        float4 Q;
        Q.x = rdin(in_state, baseb + 0, bf);
        Q.y = rdin(in_state, baseb + 1, bf);
        Q.z = rdin(in_state, baseb + 2, bf);
        Q.w = rdin(in_state, baseb + 3, bf);
        psb[tid] = Q;
        rad[tid] = rdin(in_rad, tid, bf);
        float m2 = P.z * P.z + P.w * P.w;
        #pragma unroll
        for (int off = 32; off; off >>= 1) m2 = fmaxf(m2, __shfl_down(m2, off));
        if ((tid & 63) == 0) redF[tid >> 6] = m2;
    }
    load_weights(w1, b1s, w2, b2s, w3s, b3s, inW1, inB1, inW2, inB2, inW3, inB3, bf, tid, 1024);
    if (tid == 0) candN = 0;

    float dtv = rdin(in_dt, 0, bf);
    int NS = in_nsteps[0]; if (NS > MAXSTEPS) NS = MAXSTEPS; if (NS < 0) NS = 0;

    // static tile assignment (one 6x6 tile per thread, tids 0..945)
    int myI0 = -1, myJ0 = 0;
    if (tid < NTILES) {
        int rem = tid, r = 0;
        while (rem >= NT - r) { rem -= NT - r; r++; }
        myI0 = r * 6; myJ0 = (r + rem) * 6;
    }
    __syncthreads();
    float rsum = __fadd_rn(rad[0], rad[0]);        // radii uniform

    int nc = 0;
    bool candOvf = false;
    float vcap = 0.0f, wallacc = 0.0f, margin = 0.0f;   // live in wave 0 only

    for (int s = 0; s < NS; s++) {
        float vmaxv = sqrtf(fmaxf(fmaxf(redF[0], redF[1]), fmaxf(redF[2], redF[3])));
        float theta = rsum + 0.05f + 2.0f * dtv * vmaxv + 0.15f;
        float th2 = theta * theta;
        float t_s = __fmul_rn((float)s, dtv);
        float t_e = __fadd_rn(t_s, dtv);
        float t_c = t_s;
        vcap = vmaxv;
        wallacc = 0.0f;
        margin = 2.0f * dtv * vmaxv + 0.15f;

        for (int e = 0; e < MAXEV; e++) {
            // ---------- detect phase (all 1024 threads) ----------
            unsigned long long kP = ~0ull, kW = ~0ull;
            bool fullscan = (e == 0) || (candF != 0);
            bool doAppend = (e == 0);
            if (fullscan) {
                if (myI0 >= 0) {
                    float4 Pi[6], Pj[6];
                    #pragma unroll
                    for (int a = 0; a < 6; a++) {
                        int ii = myI0 + a; ii = ii < NB ? ii : NB - 1;
                        int jj = myJ0 + a; jj = jj < NB ? jj : NB - 1;
                        Pi[a] = ps0[ii]; Pj[a] = ps0[jj];
                    }
                    #pragma unroll
                    for (int a = 0; a < 6; a++) {
                        int i = myI0 + a;
                        #pragma unroll
                        for (int bb = 0; bb < 6; bb++) {
                            int j = myJ0 + bb;
                            bool ok = (i < NB) && (j < NB) && (j > i);
                            float dx = __fsub_rn(Pj[bb].x, Pi[a].x);
                            float dy = __fsub_rn(Pj[bb].y, Pi[a].y);
                            float d2 = __fadd_rn(__fmul_rn(dx, dx), __fmul_rn(dy, dy));
                            float p1 = __fmul_rn(__fsub_rn(Pj[bb].z, Pi[a].z), dx);
                            float p2 = __fmul_rn(__fsub_rn(Pj[bb].w, Pi[a].w), dy);
                            float dot = __fadd_rn(p1, p2);
                            float mag = __fadd_rn(fabsf(p1), fabsf(p2));
                            bool appr;
                            if (fabsf(dot) < __fmul_rn(1e-5f, mag)) {
                                float dist = __fsqrt_rn(d2);
                                float den = __fadd_rn(dist, 1e-8f);
                                float ab = __fadd_rn(
                                    __fmul_rn(__fsub_rn(Pj[bb].z, Pi[a].z), __fdiv_rn(dx, den)),
                                    __fmul_rn(__fsub_rn(Pj[bb].w, Pi[a].w), __fdiv_rn(dy, den)));
                                appr = ab < 0.0f;
                            } else {
                                appr = dot < 0.0f;
                            }
                            if (ok && appr) {
                                unsigned long long key =
                                    (((unsigned long long)__float_as_uint(d2)) << 16) |
                                    (unsigned)((i << 8) | j);
                                kP = key < kP ? key : kP;
                            }
                            if (doAppend && ok && d2 < th2) {
                                int x = atomicAdd(&candN, 1);
                                if (x < CAND_MAX) cand[x] = (unsigned)((i << 8) | j);
                            }
                        }
                    }
                }
            } else {
                for (int c = tid; c < nc; c += 1024) {
                    unsigned id = cand[c];
                    pair_min(ps0, (int)(id >> 8), (int)(id & 255u), kP);
                }
            }
            {   // wall candidate: exactly one per thread (tid = ball*4+w)
                int ball = tid >> 2, w = tid & 3;
                float4 P = ps0[ball]; float r = rad[ball];
                float g; bool valid;
                if (w == 0)      { g = __fsub_rn(P.x, r); valid = P.z < 0.0f; }
                else if (w == 1) { g = __fsub_rn(__fsub_rn(10.0f, P.x), r); valid = P.z > 0.0f; }
                else if (w == 2) { g = __fsub_rn(P.y, r); valid = P.w < 0.0f; }
                else             { g = __fsub_rn(__fsub_rn(10.0f, P.y), r); valid = P.w > 0.0f; }
                if (valid) {
                    unsigned gb = __float_as_uint(g);
                    unsigned m = (unsigned)(((int)gb) >> 31) | 0x80000000u;
                    unsigned sb = gb ^ m;
                    unsigned long long key = (((unsigned long long)sb) << 16) | (unsigned)tid;
                    kW = key < kW ? key : kW;
                }
            }
            #pragma unroll
            for (int off = 32; off; off >>= 1) {
                unsigned long long o1 = shfl_down_u64(kP, off);
                unsigned long long o2 = shfl_down_u64(kW, off);
                kP = o1 < kP ? o1 : kP;
                kW = o2 < kW ? o2 : kW;
            }
            if ((tid & 63) == 0) { redP[tid >> 6] = kP; redW[tid >> 6] = kW; }
            __syncthreads();                                     // B1

            if (e == 0) {
                int ct = candN;
                candOvf = ct > CAND_MAX;
                nc = candOvf ? CAND_MAX : ct;
            }

            // ---------- decision: wave 0 only; sim0 geometry kept in registers ----------
            float g_nx = 0, g_ny = 0, g_dist = 0, g_app = 0;
            float4 gA, gB;
            if (tid < 64) {
                unsigned long long mP = redP[0], mW = redW[0];
                #pragma unroll
                for (int q = 1; q < 16; q++) {
                    mP = redP[q] < mP ? redP[q] : mP;
                    mW = redW[q] < mW ? redW[q] : mW;
                }
                float gball = 1e30f; int pi = 0, pj = 1;
                if (mP != ~0ull) {
                    unsigned id = (unsigned)(mP & 0xFFFFull);
                    pi = id >> 8; pj = id & 255u;
                    float d2 = __uint_as_float((unsigned)(mP >> 16));
                    gball = __fsub_rn(__fsqrt_rn(d2), rsum);
                }
                float gwall = 1e30f; int wb = 0, ww = 0;
                if (mW != ~0ull) {
                    unsigned id = (unsigned)(mW & 0xFFFFull);
                    wb = id >> 2; ww = id & 3u;
                    unsigned sb = (unsigned)(mW >> 16);
                    unsigned gb = (sb & 0x80000000u) ? (sb ^ 0x80000000u) : ~sb;
                    gwall = __uint_as_float(gb);
                }
                bool is_ball = gball <= gwall;
                float gap = is_ball ? gball : gwall;
                int code_ = 0; float dteB_ = 0.0f, tcn_ = t_c;
                if (!(gap > 0.05f)) {
                    float app;
                    if (is_ball) {
                        float4 A = ps0[pi], B = ps0[pj];
                        float dx = __fsub_rn(B.x, A.x), dy = __fsub_rn(B.y, A.y);
                        float nrm = __fsqrt_rn(__fadd_rn(__fmul_rn(dx, dx), __fmul_rn(dy, dy)));
                        float dvx = __fsub_rn(B.z, A.z), dvy = __fsub_rn(B.w, A.w);
                        app = -__fadd_rn(__fdiv_rn(__fmul_rn(dvx, dx), nrm),
                                         __fdiv_rn(__fmul_rn(dvy, dy), nrm));
                    } else {
                        float4 Wb = ps0[wb];
                        app = fabsf(fmaxf(Wb.z, Wb.w));
                    }
                    float t_ev = __fadd_rn(t_c, __fdiv_rn(gap, fmaxf(app, 1e-6f)));
                    if (gap <= 0.0f) {
                        code_ = is_ball ? 1 : 3;
                    } else if (app > 1e-6f && t_ev < t_e) {
                        code_ = is_ball ? 2 : 4;
                        dteB_ = (t_ev > __fadd_rn(t_c, 1e-10f)) ? __fsub_rn(t_ev, t_c) : 0.0f;
                        tcn_ = t_ev;
                    }
                }
                int ei_ = is_ball ? pi : wb;
                int ej_ = is_ball ? pj : ww;
                if (tid == 0) {
                    dI[0] = code_; dI[1] = ei_; dI[2] = ej_;
                    dF[0] = dteB_; dF[1] = tcn_;
                }
                if (code_ != 0 && code_ <= 2) {
                    // sim0 geometry (exactly R6's leader sequence), kept in registers
                    float4 A = ps0[ei_], B = ps0[ej_];
                    if (code_ == 2) {
                        A.x = __fadd_rn(A.x, __fmul_rn(A.z, dteB_));
                        A.y = __fadd_rn(A.y, __fmul_rn(A.w, dteB_));
                        B.x = __fadd_rn(B.x, __fmul_rn(B.z, dteB_));
                        B.y = __fadd_rn(B.y, __fmul_rn(B.w, dteB_));
                    }
                    gA = A; gB = B;
                    float dx = __fsub_rn(B.x, A.x), dy = __fsub_rn(B.y, A.y);
                    float nrm = __fsqrt_rn(__fadd_rn(__fmul_rn(dx, dx), __fmul_rn(dy, dy)));
                    float dist = fmaxf(nrm, 1e-8f);
                    g_nx = __fdiv_rn(dx, dist); g_ny = __fdiv_rn(dy, dist);
                    g_dist = dist;
                    float dvx = __fsub_rn(B.z, A.z), dvy = __fsub_rn(B.w, A.w);
                    g_app = __fadd_rn(__fmul_rn(dvx, g_nx), __fmul_rn(dvy, g_ny));
                }
            }
            __syncthreads();                                     // B1b (publish)

            int code = dI[0];
            if (code == 0) break;
            int ei = dI[1], ejw = dI[2];
            float dteB = dF[0];
            t_c = dF[1];
            bool integ = (code == 2) || (code == 4);

            // ---------- apply phase P2 (one barrier at end) ----------
            if (code <= 2) {
                if (tid < 64) {
                    // wave 0: sim0 MLP from registers, in-wave LDS round-trips
                    float a = __fadd_rn(__fadd_rn(__fmul_rn(g_dist, w1[2 * tid]),
                                                  __fmul_rn(g_app, w1[2 * tid + 1])), b1s[tid]);
                    sc0[4 + tid] = silu_f(a);
                    lds_fence();
                    float acc = 0.0f;
                    const float* row = &w2[tid * W2S];
                    #pragma unroll 8
                    for (int k = 0; k < HID; k++) acc = __fadd_rn(acc, __fmul_rn(sc0[4 + k], row[k]));
                    acc = __fadd_rn(acc, b2s[tid]);
                    sc0[68 + tid] = silu_f(acc);
                    lds_fence();
                    float acc3 = 0.0f;
                    for (int k = 0; k < HID; k++)
                        acc3 = __fadd_rn(acc3, __fmul_rn(sc0[68 + k], w3s[k]));
                    float impv = __fadd_rn(acc3, b3s[0]);
                    float ix = __fmul_rn(impv, g_nx), iy = __fmul_rn(impv, g_ny);
                    float nAz = __fadd_rn(gA.z, ix),  nAw = __fadd_rn(gA.w, iy);
                    float nBz = __fadd_rn(gB.z, -ix), nBw = __fadd_rn(gB.w, -iy);
                    if (tid == 0) {
                        float4 outA; outA.x = gA.x; outA.y = gA.y; outA.z = nAz; outA.w = nAw;
                        float4 outB; outB.x = gB.x; outB.y = gB.y; outB.z = nBz; outB.w = nBw;
                        ps0[ei] = outA; ps0[ejw] = outB;
                    }
                    float s1 = sqrtf(nAz * nAz + nAw * nAw);
                    float s2 = sqrtf(nBz * nBz + nBw * nBw);
                    vcap = fmaxf(vcap, fmaxf(s1, s2));
                    int nf = (candOvf || (2.0f * dtv * vcap + wallacc + 1e-3f > margin)) ? 1 : 0;
                    if (tid == 0) candF = nf;
                } else if (tid < 128) {
                    // wave 1: simb full apply (geometry + MLP), in-wave
                    int lane = tid - 64;
                    float4 A = psb[ei], B = psb[ejw];
                    if (integ) {
                        A.x = __fadd_rn(A.x, __fmul_rn(A.z, dteB));
                        A.y = __fadd_rn(A.y, __fmul_rn(A.w, dteB));
                        B.x = __fadd_rn(B.x, __fmul_rn(B.z, dteB));
                        B.y = __fadd_rn(B.y, __fmul_rn(B.w, dteB));
                    }
                    float dx = __fsub_rn(B.x, A.x), dy = __fsub_rn(B.y, A.y);
                    float nrm = __fsqrt_rn(__fadd_rn(__fmul_rn(dx, dx), __fmul_rn(dy, dy)));
                    float dist = fmaxf(nrm, 1e-8f);
                    float nx = __fdiv_rn(dx, dist), ny = __fdiv_rn(dy, dist);
                    float dvx = __fsub_rn(B.z, A.z), dvy = __fsub_rn(B.w, A.w);
                    float app2 = __fadd_rn(__fmul_rn(dvx, nx), __fmul_rn(dvy, ny));
                    float a = __fadd_rn(__fadd_rn(__fmul_rn(dist, w1[2 * lane]),
                                                  __fmul_rn(app2, w1[2 * lane + 1])), b1s[lane]);
                    scb[4 + lane] = silu_f(a);
                    lds_fence();
                    float acc = 0.0f;
                    const float* row = &w2[lane * W2S];
                    #pragma unroll 8
                    for (int k = 0; k < HID; k++) acc = __fadd_rn(acc, __fmul_rn(scb[4 + k], row[k]));
                    acc = __fadd_rn(acc, b2s[lane]);
                    scb[68 + lane] = silu_f(acc);
                    lds_fence();
                    float acc3 = 0.0f;
                    for (int k = 0; k < HID; k++)
                        acc3 = __fadd_rn(acc3, __fmul_rn(scb[68 + k], w3s[k]));
                    float impv = __fadd_rn(acc3, b3s[0]);
                    if (lane == 0) {
                        float ix = __fmul_rn(impv, nx), iy = __fmul_rn(impv, ny);
                        float4 outA; outA.x = A.x; outA.y = A.y;
                        outA.z = __fadd_rn(A.z, ix);  outA.w = __fadd_rn(A.w, iy);
                        float4 outB; outB.x = B.x; outB.y = B.y;
                        outB.z = __fadd_rn(B.z, -ix); outB.w = __fadd_rn(B.w, -iy);
                        psb[ei] = outA; psb[ejw] = outB;
                    }
                } else if (tid < 384) {
                    int t = tid - 128;
                    if (integ && t != ei && t != ejw) {
                        float4 P = ps0[t];
                        P.x = __fadd_rn(P.x, __fmul_rn(P.z, dteB));
                        P.y = __fadd_rn(P.y, __fmul_rn(P.w, dteB));
                        ps0[t] = P;
                    }
                } else if (tid < 640) {
                    int t = tid - 384;
                    if (integ && t != ei && t != ejw) {
                        float4 Q = psb[t];
                        Q.x = __fadd_rn(Q.x, __fmul_rn(Q.z, dteB));
                        Q.y = __fadd_rn(Q.y, __fmul_rn(Q.w, dteB));
                        psb[t] = Q;
                    }
                }
                __syncthreads();                                 // P2 end
            } else {
                // ---------- wall event ----------
                const float wnx[4] = {1.f, -1.f, 0.f, 0.f};
                const float wny[4] = {0.f, 0.f, 1.f, -1.f};
                const float wpv[4] = {0.f, -10.f, 0.f, -10.f};
                int w = ejw;
                if (tid < 64) {
                    float4 P = ps0[ei];
                    if (integ) {
                        P.x = __fadd_rn(P.x, __fmul_rn(P.z, dteB));
                        P.y = __fadd_rn(P.y, __fmul_rn(P.w, dteB));
                    }
                    float vn = __fadd_rn(__fmul_rn(P.z, wnx[w]), __fmul_rn(P.w, wny[w]));
                    float t2 = __fmul_rn(2.0f, vn);
                    float nvx = __fsub_rn(P.z, __fmul_rn(t2, wnx[w]));
                    float nvy = __fsub_rn(P.w, __fmul_rn(t2, wny[w]));
                    float pn = __fadd_rn(__fmul_rn(P.x, wnx[w]), __fmul_rn(P.y, wny[w]));
                    float pen = fmaxf(__fsub_rn(__fadd_rn(wpv[w], rad[ei]), pn), 0.0f);
                    float4 nP;
                    nP.x = __fadd_rn(P.x, __fmul_rn(pen, wnx[w]));
                    nP.y = __fadd_rn(P.y, __fmul_rn(pen, wny[w]));
                    nP.z = nvx; nP.w = nvy;
                    wallacc += pen;
                    int nf = (candOvf || (2.0f * dtv * vcap + wallacc + 1e-3f > margin)) ? 1 : 0;
                    if (tid == 0) { ps0[ei] = nP; candF = nf; }
                } else if (tid < 128) {
                    if (tid == 64) {
                        float4 P = psb[ei];
                        if (integ) {
                            P.x = __fadd_rn(P.x, __fmul_rn(P.z, dteB));
                            P.y = __fadd_rn(P.y, __fmul_rn(P.w, dteB));
                        }
                        float vn = __fadd_rn(__fmul_rn(P.z, wnx[w]), __fmul_rn(P.w, wny[w]));
                        float t2 = __fmul_rn(2.0f, vn);
                        float nvx = __fsub_rn(P.z, __fmul_rn(t2, wnx[w]));
                        float nvy = __fsub_rn(P.w, __fmul_rn(t2, wny[w]));
                        float pn = __fadd_rn(__fmul_rn(P.x, wnx[w]), __fmul_rn(P.y, wny[w]));
                        float pen = fmaxf(__fsub_rn(__fadd_rn(wpv[w], rad[ei]), pn), 0.0f);
                        float4 nP;
                        nP.x = __fadd_rn(P.x, __fmul_rn(pen, wnx[w]));
                        nP.y = __fadd_rn(P.y, __fmul_rn(pen, wny[w]));
                        nP.z = nvx; nP.w = nvy;
                        psb[ei] = nP;
                    }
                } else if (tid < 384) {
                    int t = tid - 128;
                    if (integ && t != ei) {
                        float4 P = ps0[t];
                        P.x = __fadd_rn(P.x, __fmul_rn(P.z, dteB));
                        P.y = __fadd_rn(P.y, __fmul_rn(P.w, dteB));
                        ps0[t] = P;
                    }
                } else if (tid < 640) {
                    int t = tid - 384;
                    if (integ && t != ei) {
                        float4 Q = psb[t];
                        Q.x = __fadd_rn(Q.x, __fmul_rn(Q.z, dteB));
                        Q.y = __fadd_rn(Q.y, __fmul_rn(Q.w, dteB));
                        psb[t] = Q;
                    }
                }
                __syncthreads();                                 // P2 end
            }
        }

        // ---------- step end: final integrate + vmax + store (fused) ----------
        float fd = (t_e > __fadd_rn(t_c, 1e-10f)) ? __fsub_rn(t_e, t_c) : 0.0f;
        if (tid < NB) {
            float4 P = ps0[tid];
            P.x = __fadd_rn(P.x, __fmul_rn(P.z, fd));
            P.y = __fadd_rn(P.y, __fmul_rn(P.w, fd));
            ps0[tid] = P;
            float m2 = P.z * P.z + P.w * P.w;
            #pragma unroll
            for (int off = 32; off; off >>= 1) m2 = fmaxf(m2, __shfl_down(m2, off));
            if ((tid & 63) == 0) redF[tid >> 6] = m2;
            if (tid == 0) candN = 0;
        } else if (tid < 2 * NB) {
            int t = tid - NB;
            float4 Q = psb[t];
            Q.x = __fadd_rn(Q.x, __fmul_rn(Q.z, fd));
            Q.y = __fadd_rn(Q.y, __fmul_rn(Q.w, fd));
            psb[t] = Q;
            long long base = ((long long)(s + 1) * NBATCH + b) * (NB * 4);
            if (bf) {
                ushort4 v;
                v.x = f2bf(Q.x); v.y = f2bf(Q.y); v.z = f2bf(Q.z); v.w = f2bf(Q.w);
                ((ushort4*)((unsigned short*)out + base))[t] = v;
            } else {
                ((float4*)((float*)out + base))[t] = Q;
            }
        }
        __syncthreads();
    }
}

extern "C" void kernel_launch(void* const* d_in, const int* in_sizes, int n_in,
                              void* d_out, int out_size, void* d_ws, size_t ws_size,
                              hipStream_t stream) {
    // inputs: 0 state, 1 radii, 2 W1, 3 b1, 4 W2, 5 b2, 6 W3, 7 b3, 8 dt, 9 n_steps
    int* ws = (int*)d_ws;
    sniff_kernel<<<1, 256, 0, stream>>>((const unsigned short*)d_in[0], ws);
    row0_kernel<<<(NBATCH * NB * 4) / 256, 256, 0, stream>>>(d_in[0], d_out, ws);
    sim_kernel<<<NBATCH, 1024, 0, stream>>>(
        d_in[0], d_in[1], d_in[2], d_in[3], d_in[4], d_in[5], d_in[6], d_in[7],
        d_in[8], (const int*)d_in[9], d_out, ws);
}